// Round 10
// baseline (487.734 us; speedup 1.0000x reference)
//
#include <hip/hip_runtime.h>
#include <hip/hip_bf16.h>
#include <math.h>

// Problem constants (fixed by the reference)
#define TT   799
#define BB   8
#define DD   512
#define HH   8
#define HDD  64
#define MMEM 6
#define RRCB 24
#define KLL  798
#define TQ   798            // query rows actually needed (row 798 unused)
#define NROWS (TQ * BB)     // 6384
#define NHEADS 64           // B*H
#define NEG_INF (-INFINITY)

#define TB   16             // t-rows per attention block
#define CH   64             // keys per MFMA chunk
#define NCH  13             // 13*64 = 832 >= 798
#define VTS  832            // v_t row stride in keys
#define NTCH 50             // t-chunks (50*16 = 800 >= TQ)
#define MINCH 7             // klen >= 430 always -> chunks 0..6 always live

static_assert(NROWS == 6384, "");

typedef __attribute__((ext_vector_type(8))) short short8;
typedef __attribute__((ext_vector_type(4))) float f32x4;

__device__ __forceinline__ unsigned short f2bf(float x) {
    union { float f; unsigned u; } c; c.f = x;
    unsigned r = c.u + 0x7FFFu + ((c.u >> 16) & 1u);   // RNE
    return (unsigned short)(r >> 16);
}
__device__ __forceinline__ float bf2f(unsigned short b) {
    union { unsigned u; float f; } c; c.u = ((unsigned)b) << 16; return c.f;
}

// mode 0 = int32 (0/1), mode 1 = float32 (0.0/1.0), mode 2 = uint8 bool.
// MUST inspect device data: in_sizes metadata does not reliably encode the
// mask dtype (v17 lesson: host-side size guess broke correctness).
__global__ void detect_mask_kernel(const unsigned int* __restrict__ a,
                                   int* __restrict__ mode)
{
    __shared__ int c0s, cHs;
    if (threadIdx.x == 0) { c0s = 0; cHs = 0; }
    __syncthreads();
    int c0 = 0, cH = 0;
    const int ND = 4096;
    for (int i = threadIdx.x; i < ND; i += blockDim.x) {
        unsigned int w = a[i];
        if (w & 0x000000FFu) c0++;
        if (w & 0xFFFFFF00u) cH++;
    }
    atomicAdd(&c0s, c0); atomicAdd(&cHs, cH);
    __syncthreads();
    if (threadIdx.x == 0)
        *mode = (cHs == 0) ? 0 : ((c0s == 0) ? 1 : 2);
}

// Fused prep: transposed (mask,rpe)->rid pack pk2[t_chunk][key][row] |
// rpe_k hi/lo split | vt tail-zero (keys 798..831) | x/mems/W hi/lo split.
#define RK_BLOCKS 36
#define PK2_BLOCKS (NTCH * 13)   // 650: one block per (t_chunk, 64-key group)
#define ZT_N (NHEADS * HDD * (VTS - KLL))   // 139,264 tail elems per buffer
#define ZT_BLOCKS ((2 * ZT_N + 255) / 256)  // 1088
__global__ __launch_bounds__(256)
void prep_kernel(const void* __restrict__ amask,
                 const int* __restrict__ rpe,
                 const int* __restrict__ mode_p,
                 unsigned int* __restrict__ pk2,
                 const float* __restrict__ rpe_k,
                 unsigned short* __restrict__ rk_hi,
                 unsigned short* __restrict__ rk_lo,
                 unsigned short* __restrict__ vt_hi,
                 unsigned short* __restrict__ vt_lo,
                 const float* __restrict__ x,
                 const float* __restrict__ mems,
                 const float* __restrict__ wq,
                 const float* __restrict__ wkv,
                 const float* __restrict__ wo,
                 unsigned short* __restrict__ xs_hi, unsigned short* __restrict__ xs_lo,
                 unsigned short* __restrict__ ms_hi, unsigned short* __restrict__ ms_lo,
                 unsigned short* __restrict__ w_hi,  unsigned short* __restrict__ w_lo)
{
    const int bid = blockIdx.x;
    const int tid = threadIdx.x;
    if (bid < PK2_BLOCKS) {
        // transposed rid pack: byte (chunk, key, row) = rid or 255.
        const int mode = *mode_p;
        const int chunk = bid / 13;
        const int kg = bid - chunk * 13;
        const int k64 = tid >> 2;          // 0..63
        const int word = tid & 3;          // covers rows word*4 .. word*4+3
        const int key = kg * 64 + k64;     // 0..831
        unsigned out = 0;
        #pragma unroll
        for (int r = 0; r < 4; ++r) {
            const int row = word * 4 + r;
            const int t = chunk * 16 + row;    // 0..799
            unsigned byte = 255u;
            if (key < KLL && t < TT) {
                size_t idx = (size_t)t * KLL + key;
                bool masked;
                if (mode == 0)      masked = (((const int*)amask)[idx] != 0);
                else if (mode == 1) masked = (((const float*)amask)[idx] != 0.f);
                else                masked = (((const unsigned char*)amask)[idx] != 0);
                byte = masked ? 255u : (unsigned)rpe[idx];
            }
            out |= byte << (8 * r);
        }
        pk2[((size_t)chunk * 832 + key) * 4 + word] = out;
    } else if (bid < PK2_BLOCKS + RK_BLOCKS) {
        int i = (bid - PK2_BLOCKS) * 256 + tid;
        if (i >= 144 * 64) return;
        int c = i >> 6;
        float v = (c < 129) ? rpe_k[i] : 0.f;
        unsigned short hi = f2bf(v);
        rk_hi[i] = hi;
        rk_lo[i] = f2bf(v - bf2f(hi));
    } else if (bid < PK2_BLOCKS + RK_BLOCKS + ZT_BLOCKS) {
        // zero vt tail keys [KLL, VTS) for every (head, hd) row, both buffers
        int i = (bid - PK2_BLOCKS - RK_BLOCKS) * 256 + tid;
        if (i >= 2 * ZT_N) return;
        unsigned short* dst = (i < ZT_N) ? vt_hi : vt_lo;
        int j = (i < ZT_N) ? i : i - ZT_N;
        int rowi = j / (VTS - KLL);
        int key = j - rowi * (VTS - KLL);
        dst[(size_t)rowi * VTS + KLL + key] = 0;
    } else {
        // hi/lo split, 4 elements/thread (regions are all multiples of 4).
        const size_t NX = (size_t)NROWS * DD;
        const size_t NM = 48 * DD;
        const size_t NW = 2048 * DD;
        size_t i = ((size_t)(bid - PK2_BLOCKS - RK_BLOCKS - ZT_BLOCKS) * 256 + tid) * 4;
        float4 v4; unsigned short *dh, *dl; size_t o;
        if (i < NX) { o = i; v4 = *(const float4*)(x + o); dh = xs_hi; dl = xs_lo; }
        else if (i < NX + NM) { o = i - NX; v4 = *(const float4*)(mems + o); dh = ms_hi; dl = ms_lo; }
        else if (i < NX + NM + NW) {
            o = i - NX - NM;
            size_t r = o >> 9;
            if (r < 512)       v4 = *(const float4*)(wq + o);
            else if (r < 1536) v4 = *(const float4*)(wkv + (o - (size_t)512 * DD));
            else               v4 = *(const float4*)(wo + (o - (size_t)1536 * DD));
            dh = w_hi; dl = w_lo;
        } else return;
        ushort4 h, lo;
        h.x = f2bf(v4.x); lo.x = f2bf(v4.x - bf2f(h.x));
        h.y = f2bf(v4.y); lo.y = f2bf(v4.y - bf2f(h.y));
        h.z = f2bf(v4.z); lo.z = f2bf(v4.z - bf2f(h.z));
        h.w = f2bf(v4.w); lo.w = f2bf(v4.w - bf2f(h.w));
        *(ushort4*)(dh + o) = h;
        *(ushort4*)(dl + o) = lo;
    }
}

// Fused Q/K/V projection, 128-row m-tiles, LDS-staged W. V outputs are
// written DIRECTLY in the transposed vt layout [head][hd][VTS] (scattered
// 2B stores, L2-absorbed) — the separate transpose_v kernel (26MB of
// traffic + a launch) is deleted. Values identical; only store addresses
// changed. Tail keys [798,832) pre-zeroed by prep.
// grid = dim3(50, 24): ny<8 -> q-path; ny>=8 -> kv-path.
__global__ __launch_bounds__(256, 4)
void proj_qkv(const unsigned short* __restrict__ xs_hi,
              const unsigned short* __restrict__ xs_lo,
              const unsigned short* __restrict__ ms_hi,
              const unsigned short* __restrict__ ms_lo,
              const unsigned short* __restrict__ w_hi,
              const unsigned short* __restrict__ w_lo,
              const float* __restrict__ bq,
              const float* __restrict__ bkv,
              unsigned short* __restrict__ q_hi, unsigned short* __restrict__ q_lo,
              unsigned short* __restrict__ k_hi, unsigned short* __restrict__ k_lo,
              unsigned short* __restrict__ vt_hi, unsigned short* __restrict__ vt_lo)
{
    const int tid = threadIdx.x;
    const int wv = tid >> 6;
    const int quad = (tid >> 4) & 3;
    const int colk = tid & 15;
    const int m0 = blockIdx.x * 128;
    const int ny = blockIdx.y;
    const bool qpath = ny < 8;
    const int n0l = (qpath ? ny : ny - 8) * 64;      // local col base
    const int wr0 = qpath ? n0l : 512 + n0l;         // physical W row base

    __shared__ unsigned short wls_h[2][64][40];
    __shared__ unsigned short wls_l[2][64][40];

    const int sn = tid >> 2;
    const int sk = (tid & 3) * 8;
    const unsigned short* wsrc_h = w_hi + (size_t)(wr0 + sn) * DD + sk;
    const unsigned short* wsrc_l = w_lo + (size_t)(wr0 + sn) * DD + sk;

    const int amA = min(m0 + wv * 16 + colk, NROWS - 1);
    const int amB = min(m0 + 64 + wv * 16 + colk, NROWS - 1);
    const unsigned short *arhA, *arlA, *arhB, *arlB;
    if (qpath) {
        arhA = xs_hi + (size_t)amA * DD; arlA = xs_lo + (size_t)amA * DD;
        arhB = xs_hi + (size_t)amB * DD; arlB = xs_lo + (size_t)amB * DD;
    } else {
        if (amA < 48) { arhA = ms_hi + (size_t)amA * DD; arlA = ms_lo + (size_t)amA * DD; }
        else          { arhA = xs_hi + (size_t)(amA - 48) * DD; arlA = xs_lo + (size_t)(amA - 48) * DD; }
        if (amB < 48) { arhB = ms_hi + (size_t)amB * DD; arlB = ms_lo + (size_t)amB * DD; }
        else          { arhB = xs_hi + (size_t)(amB - 48) * DD; arlB = xs_lo + (size_t)(amB - 48) * DD; }
    }

    f32x4 acc[2][4] = {{{0,0,0,0},{0,0,0,0},{0,0,0,0},{0,0,0,0}},
                       {{0,0,0,0},{0,0,0,0},{0,0,0,0},{0,0,0,0}}};

    {
        short8 sh = *(const short8*)(wsrc_h);
        short8 sl = *(const short8*)(wsrc_l);
        *(short8*)&wls_h[0][sn][sk] = sh;
        *(short8*)&wls_l[0][sn][sk] = sl;
    }
    __syncthreads();

    #pragma unroll 2
    for (int ks = 0; ks < 16; ++ks) {
        const int buf = ks & 1;
        const int k0 = ks * 32;
        short8 nh, nl;
        if (ks + 1 < 16) {
            nh = *(const short8*)(wsrc_h + k0 + 32);
            nl = *(const short8*)(wsrc_l + k0 + 32);
        }
        short8 ahA = *(const short8*)(arhA + k0 + quad * 8);
        short8 alA = *(const short8*)(arlA + k0 + quad * 8);
        short8 ahB = *(const short8*)(arhB + k0 + quad * 8);
        short8 alB = *(const short8*)(arlB + k0 + quad * 8);
        #pragma unroll
        for (int nt = 0; nt < 4; ++nt) {
            short8 bh = *(const short8*)&wls_h[buf][nt * 16 + colk][quad * 8];
            short8 bl = *(const short8*)&wls_l[buf][nt * 16 + colk][quad * 8];
            acc[0][nt] = __builtin_amdgcn_mfma_f32_16x16x32_bf16(ahA, bh, acc[0][nt], 0, 0, 0);
            acc[0][nt] = __builtin_amdgcn_mfma_f32_16x16x32_bf16(ahA, bl, acc[0][nt], 0, 0, 0);
            acc[0][nt] = __builtin_amdgcn_mfma_f32_16x16x32_bf16(alA, bh, acc[0][nt], 0, 0, 0);
            acc[1][nt] = __builtin_amdgcn_mfma_f32_16x16x32_bf16(ahB, bh, acc[1][nt], 0, 0, 0);
            acc[1][nt] = __builtin_amdgcn_mfma_f32_16x16x32_bf16(ahB, bl, acc[1][nt], 0, 0, 0);
            acc[1][nt] = __builtin_amdgcn_mfma_f32_16x16x32_bf16(alB, bh, acc[1][nt], 0, 0, 0);
        }
        if (ks + 1 < 16) {
            *(short8*)&wls_h[buf ^ 1][sn][sk] = nh;
            *(short8*)&wls_l[buf ^ 1][sn][sk] = nl;
        }
        __syncthreads();
    }

    #pragma unroll
    for (int half = 0; half < 2; ++half) {
        #pragma unroll
        for (int nt = 0; nt < 4; ++nt) {
            const int nn = n0l + nt * 16 + colk;
            const float bv = qpath ? bq[nn] : bkv[nn];
            #pragma unroll
            for (int reg = 0; reg < 4; ++reg) {
                const int m = m0 + half * 64 + wv * 16 + quad * 4 + reg;
                if (m >= NROWS) continue;
                float v = acc[half][nt][reg] + bv;
                int row = m >> 3, bb = m & 7;
                if (qpath) {
                    v *= 0.125f;
                    int hh = nn >> 6, hd = nn & 63;
                    size_t o = ((size_t)(bb * HH + hh) * TQ + row) * HDD + hd;
                    unsigned short hi = f2bf(v);
                    q_hi[o] = hi; q_lo[o] = f2bf(v - bf2f(hi));
                } else if (nn < DD) {
                    int hh = nn >> 6, hd = nn & 63;
                    size_t o = ((size_t)(bb * HH + hh) * KLL + row) * HDD + hd;
                    unsigned short hi = f2bf(v);
                    k_hi[o] = hi; k_lo[o] = f2bf(v - bf2f(hi));
                } else {
                    // direct transposed store: vt[(head*HDD + hd)*VTS + key]
                    int n2 = nn - DD;
                    int hh = n2 >> 6, hd = n2 & 63;
                    size_t o = ((size_t)((bb * HH + hh) * HDD + hd)) * VTS + row;
                    unsigned short hi = f2bf(v);
                    vt_hi[o] = hi; vt_lo[o] = f2bf(v - bf2f(hi));
                }
            }
        }
    }
}

// Output projection: A = ao, W = wo (base passed), out f32 + tanh tail rows.
// Same 128-row LDS-staged structure as proj_qkv.
__global__ __launch_bounds__(256, 4)
void proj_out(const unsigned short* __restrict__ a_hi,
              const unsigned short* __restrict__ a_lo,
              const unsigned short* __restrict__ w_hi,
              const unsigned short* __restrict__ w_lo,
              const float* __restrict__ bias,
              float* __restrict__ out_f)
{
    const int tid = threadIdx.x;
    const int wv = tid >> 6;
    const int quad = (tid >> 4) & 3;
    const int colk = tid & 15;
    const int m0 = blockIdx.x * 128;
    const int n0 = blockIdx.y * 64;

    __shared__ unsigned short wls_h[2][64][40];
    __shared__ unsigned short wls_l[2][64][40];

    const int sn = tid >> 2;
    const int sk = (tid & 3) * 8;
    const unsigned short* wsrc_h = w_hi + (size_t)(n0 + sn) * DD + sk;
    const unsigned short* wsrc_l = w_lo + (size_t)(n0 + sn) * DD + sk;

    const int amA = min(m0 + wv * 16 + colk, NROWS - 1);
    const int amB = min(m0 + 64 + wv * 16 + colk, NROWS - 1);
    const unsigned short* arhA = a_hi + (size_t)amA * DD;
    const unsigned short* arlA = a_lo + (size_t)amA * DD;
    const unsigned short* arhB = a_hi + (size_t)amB * DD;
    const unsigned short* arlB = a_lo + (size_t)amB * DD;

    f32x4 acc[2][4] = {{{0,0,0,0},{0,0,0,0},{0,0,0,0},{0,0,0,0}},
                       {{0,0,0,0},{0,0,0,0},{0,0,0,0},{0,0,0,0}}};

    {
        short8 sh = *(const short8*)(wsrc_h);
        short8 sl = *(const short8*)(wsrc_l);
        *(short8*)&wls_h[0][sn][sk] = sh;
        *(short8*)&wls_l[0][sn][sk] = sl;
    }
    __syncthreads();

    #pragma unroll 2
    for (int ks = 0; ks < 16; ++ks) {
        const int buf = ks & 1;
        const int k0 = ks * 32;
        short8 nh, nl;
        if (ks + 1 < 16) {
            nh = *(const short8*)(wsrc_h + k0 + 32);
            nl = *(const short8*)(wsrc_l + k0 + 32);
        }
        short8 ahA = *(const short8*)(arhA + k0 + quad * 8);
        short8 alA = *(const short8*)(arlA + k0 + quad * 8);
        short8 ahB = *(const short8*)(arhB + k0 + quad * 8);
        short8 alB = *(const short8*)(arlB + k0 + quad * 8);
        #pragma unroll
        for (int nt = 0; nt < 4; ++nt) {
            short8 bh = *(const short8*)&wls_h[buf][nt * 16 + colk][quad * 8];
            short8 bl = *(const short8*)&wls_l[buf][nt * 16 + colk][quad * 8];
            acc[0][nt] = __builtin_amdgcn_mfma_f32_16x16x32_bf16(ahA, bh, acc[0][nt], 0, 0, 0);
            acc[0][nt] = __builtin_amdgcn_mfma_f32_16x16x32_bf16(ahA, bl, acc[0][nt], 0, 0, 0);
            acc[0][nt] = __builtin_amdgcn_mfma_f32_16x16x32_bf16(alA, bh, acc[0][nt], 0, 0, 0);
            acc[1][nt] = __builtin_amdgcn_mfma_f32_16x16x32_bf16(ahB, bh, acc[1][nt], 0, 0, 0);
            acc[1][nt] = __builtin_amdgcn_mfma_f32_16x16x32_bf16(ahB, bl, acc[1][nt], 0, 0, 0);
            acc[1][nt] = __builtin_amdgcn_mfma_f32_16x16x32_bf16(alB, bh, acc[1][nt], 0, 0, 0);
        }
        if (ks + 1 < 16) {
            *(short8*)&wls_h[buf ^ 1][sn][sk] = nh;
            *(short8*)&wls_l[buf ^ 1][sn][sk] = nl;
        }
        __syncthreads();
    }

    #pragma unroll
    for (int half = 0; half < 2; ++half) {
        #pragma unroll
        for (int nt = 0; nt < 4; ++nt) {
            const int nn = n0 + nt * 16 + colk;
            const float bv = bias[nn];
            #pragma unroll
            for (int reg = 0; reg < 4; ++reg) {
                const int m = m0 + half * 64 + wv * 16 + quad * 4 + reg;
                if (m >= NROWS) continue;
                float v = acc[half][nt][reg] + bv;
                int row = m >> 3;
                if (row >= TQ - MMEM) v = tanhf(v);
                out_f[(size_t)m * DD + nn] = v;
            }
        }
    }
}

// Attention: v14 EXACT (best measured: 263-274 us, four consistent runs).
__global__ __launch_bounds__(256, 3)
void attn_kernel(const unsigned short* __restrict__ qh_g,
                 const unsigned short* __restrict__ ql_g,
                 const unsigned short* __restrict__ kh_g,
                 const unsigned short* __restrict__ kl_g,
                 const unsigned short* __restrict__ vt_hi,
                 const unsigned short* __restrict__ vt_lo,
                 const int* __restrict__ lengths,
                 const unsigned int* __restrict__ pk2,
                 const unsigned short* __restrict__ rk_hi,
                 const unsigned short* __restrict__ rk_lo,
                 const float* __restrict__ rpe_v,
                 unsigned short* __restrict__ ao_hi,
                 unsigned short* __restrict__ ao_lo)
{
    // XCD-aware decode: xcd = id&7 fixed per head; t-chunks consecutive.
    const int id = blockIdx.x;
    const int xcd = id & 7;
    const int grp = id >> 3;             // 0..399
    const int t_chunk = grp % NTCH;
    const int n = (grp / NTCH) * 8 + xcd; // head index 0..63
    const int t0 = t_chunk * TB;
    const int rows = min(TB, TQ - t0);
    const int b = n >> 3;
    const int h = n & 7;
    const int tid = threadIdx.x;
    const int wv = tid >> 6;
    const int quad = (tid >> 4) & 3;
    const int colk = tid & 15;
    const int myk = wv * 16 + colk;

    __shared__ float qrk_l[TB][132];                 // qrk, then pr buckets (8448 B)
    __shared__ unsigned short p_hi[2][TB][72];       // 4608 B
    __shared__ unsigned short p_lo[2][TB][72];       // 4608 B
    __shared__ float4 stats_l[4][TB];                // 1024 B

    const int klen = lengths[b] + MMEM + RRCB;
    const int nch_live = (klen + CH - 1) / CH;       // block-uniform, 7..13
    const unsigned* pkg = pk2 + (size_t)t_chunk * 832 * 4;  // u32 units

#define LIVE(c) ((c) < MINCH || (c) < nch_live)

    // A fragments (Q), direct global, held all kernel. A row = query row colk.
    const int qrow = t0 + min(colk, rows - 1);
    const size_t qo = ((size_t)n * TQ + qrow) * HDD;
    short8 ah0 = *(const short8*)(qh_g + qo + quad * 8);
    short8 ah1 = *(const short8*)(qh_g + qo + 32 + quad * 8);
    short8 al0 = *(const short8*)(ql_g + qo + quad * 8);
    short8 al1 = *(const short8*)(ql_g + qo + 32 + quad * 8);

    // qrk via MFMA: wave wv does rpe_k row-tiles wv, wv+4, wv+8
    for (int t = wv; t < 9; t += 4) {
        const size_t rb = (size_t)(t * 16 + colk) * 64;
        short8 bh0 = *(const short8*)(rk_hi + rb + quad * 8);
        short8 bh1 = *(const short8*)(rk_hi + rb + 32 + quad * 8);
        short8 bl0 = *(const short8*)(rk_lo + rb + quad * 8);
        short8 bl1 = *(const short8*)(rk_lo + rb + 32 + quad * 8);
        f32x4 c4 = {0.f, 0.f, 0.f, 0.f};
        c4 = __builtin_amdgcn_mfma_f32_16x16x32_bf16(ah0, bh0, c4, 0, 0, 0);
        c4 = __builtin_amdgcn_mfma_f32_16x16x32_bf16(ah1, bh1, c4, 0, 0, 0);
        c4 = __builtin_amdgcn_mfma_f32_16x16x32_bf16(ah0, bl0, c4, 0, 0, 0);
        c4 = __builtin_amdgcn_mfma_f32_16x16x32_bf16(ah1, bl1, c4, 0, 0, 0);
        c4 = __builtin_amdgcn_mfma_f32_16x16x32_bf16(al0, bh0, c4, 0, 0, 0);
        c4 = __builtin_amdgcn_mfma_f32_16x16x32_bf16(al1, bh1, c4, 0, 0, 0);
        int c = t * 16 + colk;
        if (c <= 128) {
            #pragma unroll
            for (int reg = 0; reg < 4; ++reg) qrk_l[quad * 4 + reg][c] = c4[reg];
        }
    }
    __syncthreads();

    // ---- pass A: QK^T MFMA, record scores + max (live chunks only) ----
    float s_reg[NCH][4];
    float mx[4] = {-1e30f, -1e30f, -1e30f, -1e30f};

    #pragma unroll
    for (int cc = 0; cc < NCH; ++cc) {
        if (LIVE(cc)) {
            const int key = cc * CH + myk;
            const int krow = min(key, KLL - 1);
            const size_t ko = ((size_t)n * KLL + krow) * HDD;
            const unsigned r4 = pkg[key * 4 + quad];   // early: hides under MFMAs
            short8 bh0 = *(const short8*)(kh_g + ko + quad * 8);
            short8 bh1 = *(const short8*)(kh_g + ko + 32 + quad * 8);
            short8 bl0 = *(const short8*)(kl_g + ko + quad * 8);
            short8 bl1 = *(const short8*)(kl_g + ko + 32 + quad * 8);
            f32x4 c4a = {0.f, 0.f, 0.f, 0.f};
            f32x4 c4b = {0.f, 0.f, 0.f, 0.f};
            c4a = __builtin_amdgcn_mfma_f32_16x16x32_bf16(ah0, bh0, c4a, 0, 0, 0);
            c4b = __builtin_amdgcn_mfma_f32_16x16x32_bf16(ah1, bh1, c4b, 0, 0, 0);
            c4a = __builtin_amdgcn_mfma_f32_16x16x32_bf16(ah0, bl0, c4a, 0, 0, 0);
            c4b = __builtin_amdgcn_mfma_f32_16x16x32_bf16(ah1, bl1, c4b, 0, 0, 0);
            c4a = __builtin_amdgcn_mfma_f32_16x16x32_bf16(al0, bh0, c4a, 0, 0, 0);
            c4b = __builtin_amdgcn_mfma_f32_16x16x32_bf16(al1, bh1, c4b, 0, 0, 0);

            const bool vkey = (key < klen);
            #pragma unroll
            for (int reg = 0; reg < 4; ++reg) {
                const int row = quad * 4 + reg;
                const unsigned rid = (r4 >> (8 * reg)) & 255u;
                const float qv = qrk_l[row][min(rid, 128u)];   // clamped gather
                float s = (c4a[reg] + c4b[reg]) + qv;
                const bool ok = vkey && (row < rows) && (rid != 255u);
                s = ok ? s : -1e30f;
                mx[reg] = fmaxf(mx[reg], s);
                s_reg[cc][reg] = s;
            }
        } else {
            #pragma unroll
            for (int reg = 0; reg < 4; ++reg) s_reg[cc][reg] = -1e30f;
        }
    }

    // max merge: shfl16 then cross-wave
    #pragma unroll
    for (int reg = 0; reg < 4; ++reg)
        #pragma unroll
        for (int d = 1; d < 16; d <<= 1) mx[reg] = fmaxf(mx[reg], __shfl_xor(mx[reg], d, 16));
    if (colk == 0) {
        #pragma unroll
        for (int reg = 0; reg < 4; ++reg)
            stats_l[wv][quad * 4 + reg] = make_float4(mx[reg], 0.f, 0.f, 0.f);
    }
    __syncthreads();
    if (tid < TB) {
        float M = fmaxf(fmaxf(stats_l[0][tid].x, stats_l[1][tid].x),
                        fmaxf(stats_l[2][tid].x, stats_l[3][tid].x));
        stats_l[0][tid].x = M;
    }
    __syncthreads();

    // e-sweep (branchless): e = exp(s - M) (underflows to 0 for dead),
    // overwrite s_reg; accumulate l, l2, count (count via select).
    float Mr[4], l[4] = {0,0,0,0}, l2[4] = {0,0,0,0}, cn[4] = {0,0,0,0};
    #pragma unroll
    for (int reg = 0; reg < 4; ++reg) Mr[reg] = stats_l[0][quad * 4 + reg].x;
    #pragma unroll
    for (int cc = 0; cc < NCH; ++cc) {
        if (LIVE(cc)) {
            #pragma unroll
            for (int reg = 0; reg < 4; ++reg) {
                float s = s_reg[cc][reg];
                float e = expf(s - Mr[reg]);
                cn[reg] += (s > -1e29f) ? 1.f : 0.f;
                l[reg] += e;
                l2[reg] = fmaf(e, e, l2[reg]);
                s_reg[cc][reg] = e;
            }
        }
    }
    #pragma unroll
    for (int reg = 0; reg < 4; ++reg)
        #pragma unroll
        for (int d = 1; d < 16; d <<= 1) {
            l[reg]  += __shfl_xor(l[reg], d, 16);
            l2[reg] += __shfl_xor(l2[reg], d, 16);
            cn[reg] += __shfl_xor(cn[reg], d, 16);
        }
    if (colk == 0) {
        #pragma unroll
        for (int reg = 0; reg < 4; ++reg)
            stats_l[wv][quad * 4 + reg] = make_float4(Mr[reg], l[reg], l2[reg], cn[reg]);
    }
    __syncthreads();
    if (tid < TB) {
        float L = 0.f, L2 = 0.f, C = 0.f;
        #pragma unroll
        for (int w = 0; w < 4; ++w) {
            float4 s4 = stats_l[w][tid];
            L += s4.y; L2 += s4.z; C += s4.w;
        }
        float inv = (L > 0.f) ? 1.f / L : 0.f;
        float mean = 1.f / (C + 1e-8f);
        float sump2 = L2 * inv * inv;
        float var = (sump2 - 2.f * mean + C * mean * mean) / (C - 1.f + 1e-8f);
        var = fmaxf(var, 0.f);
        float thr = mean - 0.5f * sqrtf(var);
        stats_l[0][tid] = make_float4(stats_l[0][tid].x, inv, thr, 0.f);
    }
    // zero pr (qrk_l reuse; scores are stored, qrk dead after pass A)
    for (int i = tid; i < TB * 132; i += 256) ((float*)qrk_l)[i] = 0.f;
    __syncthreads();

    // ---- pass B: p = e*inv, threshold, buckets, PV via MFMA (live only) ----
    float inv_r[4], thr_r[4];
    #pragma unroll
    for (int reg = 0; reg < 4; ++reg) {
        float4 s4 = stats_l[0][quad * 4 + reg];
        inv_r[reg] = s4.y; thr_r[reg] = s4.z;
    }
    float sig[4] = {0.f, 0.f, 0.f, 0.f};
    f32x4 oaccA = {0.f, 0.f, 0.f, 0.f};
    f32x4 oaccB = {0.f, 0.f, 0.f, 0.f};

    auto computeP = [&](int cc, int buf, unsigned r4) {
        #pragma unroll
        for (int reg = 0; reg < 4; ++reg) {
            const int row = quad * 4 + reg;
            float p = s_reg[cc][reg] * inv_r[reg];
            if (p < thr_r[reg]) p = 0.f;
            sig[reg] += p;
            if (p > 0.f) {
                unsigned rid = (r4 >> (8 * reg)) & 255u;
                atomicAdd(&qrk_l[row][rid], p);
            }
            unsigned short ph = f2bf(p);
            p_hi[buf][row][myk] = ph;
            p_lo[buf][row][myk] = f2bf(p - bf2f(ph));
        }
    };

    // V fragment registers (current + prefetch handled per iteration)
    short8 vh0, vh1, vl0, vl1;
    {
        const size_t vbase = ((size_t)n * HDD + wv * 16 + colk) * VTS;
        vh0 = *(const short8*)(vt_hi + vbase + quad * 8);
        vh1 = *(const short8*)(vt_hi + vbase + 32 + quad * 8);
        vl0 = *(const short8*)(vt_lo + vbase + quad * 8);
        vl1 = *(const short8*)(vt_lo + vbase + 32 + quad * 8);
    }
    computeP(0, 0, pkg[myk * 4 + quad]);
    __syncthreads();
    #pragma unroll
    for (int cc = 0; cc < NCH; ++cc) {
        if (LIVE(cc)) {
            const bool nlive = (cc + 1 < NCH) && LIVE(cc + 1);
            // prefetch next chunk's V frags + pk word (global: no barrier dep)
            short8 nvh0, nvh1, nvl0, nvl1; unsigned nr4 = 0;
            if (nlive) {
                const size_t vbase = ((size_t)n * HDD + wv * 16 + colk) * VTS
                                   + (cc + 1) * CH;
                nvh0 = *(const short8*)(vt_hi + vbase + quad * 8);
                nvh1 = *(const short8*)(vt_hi + vbase + 32 + quad * 8);
                nvl0 = *(const short8*)(vt_lo + vbase + quad * 8);
                nvl1 = *(const short8*)(vt_lo + vbase + 32 + quad * 8);
                nr4 = pkg[((cc + 1) * CH + myk) * 4 + quad];
            }
            const int buf = cc & 1;
            short8 ph0 = *(const short8*)&p_hi[buf][colk][quad * 8];
            short8 ph1 = *(const short8*)&p_hi[buf][colk][32 + quad * 8];
            short8 pl0 = *(const short8*)&p_lo[buf][colk][quad * 8];
            short8 pl1 = *(const short8*)&p_lo[buf][colk][32 + quad * 8];
            oaccA = __builtin_amdgcn_mfma_f32_16x16x32_bf16(vh0, ph0, oaccA, 0, 0, 0);
            oaccB = __builtin_amdgcn_mfma_f32_16x16x32_bf16(vh1, ph1, oaccB, 0, 0, 0);
            oaccA = __builtin_amdgcn_mfma_f32_16x16x32_bf16(vh0, pl0, oaccA, 0, 0, 0);
            oaccB = __builtin_amdgcn_mfma_f32_16x16x32_bf16(vh1, pl1, oaccB, 0, 0, 0);
            oaccA = __builtin_amdgcn_mfma_f32_16x16x32_bf16(vl0, ph0, oaccA, 0, 0, 0);
            oaccB = __builtin_amdgcn_mfma_f32_16x16x32_bf16(vl1, ph1, oaccB, 0, 0, 0);
            if (nlive) computeP(cc + 1, (cc + 1) & 1, nr4);
            __syncthreads();
            if (nlive) { vh0 = nvh0; vh1 = nvh1; vl0 = nvl0; vl1 = nvl1; }
        }
    }

    // survivor-sum merge
    #pragma unroll
    for (int reg = 0; reg < 4; ++reg)
        #pragma unroll
        for (int d = 1; d < 16; d <<= 1) sig[reg] += __shfl_xor(sig[reg], d, 16);
    if (colk == 0) {
        #pragma unroll
        for (int reg = 0; reg < 4; ++reg)
            stats_l[wv][quad * 4 + reg].w = sig[reg];
    }
    __syncthreads();
    if (tid < TB) {
        float S = stats_l[0][tid].w + stats_l[1][tid].w + stats_l[2][tid].w + stats_l[3][tid].w;
        stats_l[0][tid].w = (S > 0.f) ? 1.f / S : 0.f;
    }
    __syncthreads();

    // output: lane owns O[row=colk][hd = wv*16 + quad*4 .. +3], bf16 hi/lo.
    // Branchless bucket dot: p == 0 contributes exactly 0, loads pipeline.
    if (colk < rows) {
        float4 ar = {0.f, 0.f, 0.f, 0.f};
        const int hdb = wv * 16 + quad * 4;
        #pragma unroll 4
        for (int c = 0; c < 129; ++c) {
            float p = qrk_l[colk][c];
            float4 v4 = *(const float4*)(rpe_v + (size_t)c * HDD + hdb);
            ar.x = fmaf(p, v4.x, ar.x);
            ar.y = fmaf(p, v4.y, ar.y);
            ar.z = fmaf(p, v4.z, ar.z);
            ar.w = fmaf(p, v4.w, ar.w);
        }
        const float invS = stats_l[0][colk].w;
        float o0 = (2.f * (oaccA[0] + oaccB[0]) + ar.x) * invS;
        float o1 = (2.f * (oaccA[1] + oaccB[1]) + ar.y) * invS;
        float o2 = (2.f * (oaccA[2] + oaccB[2]) + ar.z) * invS;
        float o3 = (2.f * (oaccA[3] + oaccB[3]) + ar.w) * invS;
        size_t oo = ((size_t)(t0 + colk) * BB + b) * DD + h * HDD + hdb;
        ushort4 oh, ol;
        oh.x = f2bf(o0); ol.x = f2bf(o0 - bf2f(oh.x));
        oh.y = f2bf(o1); ol.y = f2bf(o1 - bf2f(oh.y));
        oh.z = f2bf(o2); ol.z = f2bf(o2 - bf2f(oh.z));
        oh.w = f2bf(o3); ol.w = f2bf(o3 - bf2f(oh.w));
        *(ushort4*)(ao_hi + oo) = oh;
        *(ushort4*)(ao_lo + oo) = ol;
    }
#undef LIVE
}

extern "C" void kernel_launch(void* const* d_in, const int* in_sizes, int n_in,
                              void* d_out, int out_size, void* d_ws, size_t ws_size,
                              hipStream_t stream) {
    const float*          x      = (const float*)d_in[0];
    const int*            lengths= (const int*)d_in[1];
    const float*          mems   = (const float*)d_in[2];
    const void*           amask  = (const void*)d_in[3];
    const int*            rpe    = (const int*)d_in[4];
    const float*          wq     = (const float*)d_in[6];
    const float*          bq     = (const float*)d_in[7];
    const float*          wkv    = (const float*)d_in[8];
    const float*          bkv    = (const float*)d_in[9];
    const float*          wo     = (const float*)d_in[10];
    const float*          bo     = (const float*)d_in[11];
    const float*          rpe_k  = (const float*)d_in[12];
    const float*          rpe_v  = (const float*)d_in[13];

    const size_t NE = (size_t)NROWS * DD;           // 3,268,608
    const size_t VTN = (size_t)NHEADS * HDD * VTS;  // 3,407,872

    char* p = (char*)d_ws;
    unsigned short* q_hi = (unsigned short*)p;  p += NE * 2;
    unsigned short* q_lo = (unsigned short*)p;  p += NE * 2;
    // xs/ms region (proj inputs, dead after proj_qkv) -> reused as ao
    char* xsr = p;                              p += NE * 4 + (size_t)48 * DD * 4;
    unsigned short* xs_hi = (unsigned short*)xsr;
    unsigned short* xs_lo = xs_hi + NE;
    unsigned short* ms_hi = xs_lo + NE;
    unsigned short* ms_lo = ms_hi + 48 * DD;
    unsigned short* ao_hi = (unsigned short*)xsr;   // alias: xs dead after proj
    unsigned short* ao_lo = ao_hi + NE;
    unsigned short* vt_hi = (unsigned short*)p; p += VTN * 2;  // own region now
    unsigned short* vt_lo = (unsigned short*)p; p += VTN * 2;
    unsigned short* w_hi = (unsigned short*)p;  p += (size_t)2048 * DD * 2;
    unsigned short* w_lo = (unsigned short*)p;  p += (size_t)2048 * DD * 2;
    unsigned short* k_hi = (unsigned short*)p;  p += NE * 2;
    unsigned short* k_lo = (unsigned short*)p;  p += NE * 2;
    unsigned short* rk_hi = (unsigned short*)p; p += 144 * 64 * 2;
    unsigned short* rk_lo = (unsigned short*)p; p += 144 * 64 * 2;
    unsigned int*   pk2   = (unsigned int*)p;   p += (size_t)NTCH * 832 * 16;
    int* mmode = (int*)p;

    detect_mask_kernel<<<1, 1024, 0, stream>>>((const unsigned int*)amask, mmode);
    {
        const size_t sp_total = NE + (size_t)48 * DD + (size_t)2048 * DD;  // 4,341,760
        const int sp_blocks = (int)((sp_total + 1023) / 1024);             // 4,240
        prep_kernel<<<PK2_BLOCKS + RK_BLOCKS + ZT_BLOCKS + sp_blocks, 256, 0, stream>>>(
            amask, rpe, mmode, pk2,
            rpe_k, rk_hi, rk_lo,
            vt_hi, vt_lo,
            x, mems, wq, wkv, wo,
            xs_hi, xs_lo, ms_hi, ms_lo, w_hi, w_lo);
    }
    proj_qkv<<<dim3(50, 24), 256, 0, stream>>>(
        xs_hi, xs_lo, ms_hi, ms_lo, w_hi, w_lo, bq, bkv,
        q_hi, q_lo, k_hi, k_lo, vt_hi, vt_lo);
    attn_kernel<<<3200, 256, 0, stream>>>(
        q_hi, q_lo, k_hi, k_lo, vt_hi, vt_lo, lengths, pk2, rk_hi, rk_lo, rpe_v, ao_hi, ao_lo);
    proj_out<<<dim3(50, 8), 256, 0, stream>>>(
        ao_hi, ao_lo, w_hi + (size_t)1536 * DD, w_lo + (size_t)1536 * DD, bo,
        (float*)d_out);
}

// Round 11
// 455.735 us; speedup vs baseline: 1.0702x; 1.0702x over previous
//
#include <hip/hip_runtime.h>
#include <hip/hip_bf16.h>
#include <math.h>

// Problem constants (fixed by the reference)
#define TT   799
#define BB   8
#define DD   512
#define HH   8
#define HDD  64
#define MMEM 6
#define RRCB 24
#define KLL  798
#define TQ   798            // query rows actually needed (row 798 unused)
#define NROWS (TQ * BB)     // 6384
#define NHEADS 64           // B*H
#define NEG_INF (-INFINITY)

#define TB   16             // t-rows per attention block
#define CH   64             // keys per MFMA chunk
#define NCH  13             // 13*64 = 832 >= 798
#define VTS  832            // v_t row stride in keys
#define NTCH 50             // t-chunks (50*16 = 800 >= TQ)
#define MINCH 7             // klen >= 430 always -> chunks 0..6 always live

static_assert(NROWS == 6384, "");

typedef __attribute__((ext_vector_type(8))) short short8;
typedef __attribute__((ext_vector_type(4))) float f32x4;

__device__ __forceinline__ unsigned short f2bf(float x) {
    union { float f; unsigned u; } c; c.f = x;
    unsigned r = c.u + 0x7FFFu + ((c.u >> 16) & 1u);   // RNE
    return (unsigned short)(r >> 16);
}
__device__ __forceinline__ float bf2f(unsigned short b) {
    union { unsigned u; float f; } c; c.u = ((unsigned)b) << 16; return c.f;
}

// Fused prep: transposed (mask,rpe)->rid pack pk2[t_chunk][key][row] |
// rpe_k hi/lo split | x/mems/W hi/lo split (float4-vectorized).
// Mask dtype (mode 0 = int32 0/1, 1 = float32, 2 = uint8) is detected
// IN-BLOCK from the first 4096 mask words (16KB, L2-hot, deterministic,
// block-uniform) — the former 1-block detect kernel launch is deleted.
// v17 lesson: dtype MUST come from device data, not in_sizes metadata.
#define RK_BLOCKS 36
#define PK2_BLOCKS (NTCH * 13)   // 650: one block per (t_chunk, 64-key group)
__global__ __launch_bounds__(256)
void prep_kernel(const void* __restrict__ amask,
                 const int* __restrict__ rpe,
                 unsigned int* __restrict__ pk2,
                 const float* __restrict__ rpe_k,
                 unsigned short* __restrict__ rk_hi,
                 unsigned short* __restrict__ rk_lo,
                 const float* __restrict__ x,
                 const float* __restrict__ mems,
                 const float* __restrict__ wq,
                 const float* __restrict__ wkv,
                 const float* __restrict__ wo,
                 unsigned short* __restrict__ xs_hi, unsigned short* __restrict__ xs_lo,
                 unsigned short* __restrict__ ms_hi, unsigned short* __restrict__ ms_lo,
                 unsigned short* __restrict__ w_hi,  unsigned short* __restrict__ w_lo)
{
    const int bid = blockIdx.x;
    const int tid = threadIdx.x;
    if (bid < PK2_BLOCKS) {
        // in-block mask-dtype detection (identical result in every block)
        __shared__ int c0s, cHs;
        if (tid == 0) { c0s = 0; cHs = 0; }
        __syncthreads();
        {
            int c0 = 0, cH = 0;
            const unsigned* aw = (const unsigned*)amask;
            for (int i = tid; i < 4096; i += 256) {
                unsigned w = aw[i];
                if (w & 0x000000FFu) c0++;
                if (w & 0xFFFFFF00u) cH++;
            }
            atomicAdd(&c0s, c0); atomicAdd(&cHs, cH);
        }
        __syncthreads();
        const int mode = (cHs == 0) ? 0 : ((c0s == 0) ? 1 : 2);

        // transposed rid pack: byte (chunk, key, row) = rid or 255.
        const int chunk = bid / 13;
        const int kg = bid - chunk * 13;
        const int k64 = tid >> 2;          // 0..63
        const int word = tid & 3;          // covers rows word*4 .. word*4+3
        const int key = kg * 64 + k64;     // 0..831
        unsigned out = 0;
        #pragma unroll
        for (int r = 0; r < 4; ++r) {
            const int row = word * 4 + r;
            const int t = chunk * 16 + row;    // 0..799
            unsigned byte = 255u;
            if (key < KLL && t < TT) {
                size_t idx = (size_t)t * KLL + key;
                bool masked;
                if (mode == 0)      masked = (((const int*)amask)[idx] != 0);
                else if (mode == 1) masked = (((const float*)amask)[idx] != 0.f);
                else                masked = (((const unsigned char*)amask)[idx] != 0);
                byte = masked ? 255u : (unsigned)rpe[idx];
            }
            out |= byte << (8 * r);
        }
        pk2[((size_t)chunk * 832 + key) * 4 + word] = out;
    } else if (bid < PK2_BLOCKS + RK_BLOCKS) {
        int i = (bid - PK2_BLOCKS) * 256 + tid;
        if (i >= 144 * 64) return;
        int c = i >> 6;
        float v = (c < 129) ? rpe_k[i] : 0.f;
        unsigned short hi = f2bf(v);
        rk_hi[i] = hi;
        rk_lo[i] = f2bf(v - bf2f(hi));
    } else {
        // hi/lo split, 4 elements/thread (regions are all multiples of 4).
        const size_t NX = (size_t)NROWS * DD;
        const size_t NM = 48 * DD;
        const size_t NW = 2048 * DD;
        size_t i = ((size_t)(bid - PK2_BLOCKS - RK_BLOCKS) * 256 + tid) * 4;
        float4 v4; unsigned short *dh, *dl; size_t o;
        if (i < NX) { o = i; v4 = *(const float4*)(x + o); dh = xs_hi; dl = xs_lo; }
        else if (i < NX + NM) { o = i - NX; v4 = *(const float4*)(mems + o); dh = ms_hi; dl = ms_lo; }
        else if (i < NX + NM + NW) {
            o = i - NX - NM;
            size_t r = o >> 9;
            if (r < 512)       v4 = *(const float4*)(wq + o);
            else if (r < 1536) v4 = *(const float4*)(wkv + (o - (size_t)512 * DD));
            else               v4 = *(const float4*)(wo + (o - (size_t)1536 * DD));
            dh = w_hi; dl = w_lo;
        } else return;
        ushort4 h, lo;
        h.x = f2bf(v4.x); lo.x = f2bf(v4.x - bf2f(h.x));
        h.y = f2bf(v4.y); lo.y = f2bf(v4.y - bf2f(h.y));
        h.z = f2bf(v4.z); lo.z = f2bf(v4.z - bf2f(h.z));
        h.w = f2bf(v4.w); lo.w = f2bf(v4.w - bf2f(h.w));
        *(ushort4*)(dh + o) = h;
        *(ushort4*)(dl + o) = lo;
    }
}

// v row-major bf16 hi/lo [head][key][hd] -> v_t [head][hd][VTS] (keys 798..831 zero)
__global__ __launch_bounds__(256)
void transpose_v_kernel(const unsigned short* __restrict__ vr_hi,
                        const unsigned short* __restrict__ vr_lo,
                        unsigned short* __restrict__ vt_hi,
                        unsigned short* __restrict__ vt_lo)
{
    const int head = blockIdx.y;
    const int kb = blockIdx.x * 64;
    __shared__ unsigned short th[64][66];
    __shared__ unsigned short tl[64][66];
    const int tid = threadIdx.x;
    for (int i = tid; i < 64 * 64; i += 256) {
        int ky = i >> 6, hd = i & 63;
        int key = kb + ky;
        unsigned short hv = 0, lv = 0;
        if (key < KLL) {
            size_t o = ((size_t)head * KLL + key) * HDD + hd;
            hv = vr_hi[o]; lv = vr_lo[o];
        }
        th[ky][hd] = hv; tl[ky][hd] = lv;
    }
    __syncthreads();
    for (int i = tid; i < 64 * 64; i += 256) {
        int hd = i >> 6, ky = i & 63;
        size_t o = ((size_t)head * HDD + hd) * VTS + kb + ky;
        vt_hi[o] = th[ky][hd];
        vt_lo[o] = tl[ky][hd];
    }
}

// MFMA GEMM v2: LDS-staged W (v16's proven scheme). 64n x 32k W tile
// (hi+lo) staged to LDS once per k-step (reg-staged, double-buffered,
// 40-short padded rows); all 4 waves read frags via ds_read_b128.
// MODE 0: A = xs, out q hi/lo (scaled 0.125). MODE 1: A = mem_rc (ms|xs),
// out k hi/lo (n<512) or vr hi/lo. MODE 2: A = ao, out f32 (+tanh tail rows).
template<int MODE>
__global__ __launch_bounds__(256, 4)
void mfma_proj(const unsigned short* __restrict__ a_hi,
               const unsigned short* __restrict__ a_lo,
               const unsigned short* __restrict__ ms_hi,
               const unsigned short* __restrict__ ms_lo,
               const unsigned short* __restrict__ w_hi,
               const unsigned short* __restrict__ w_lo,
               const float* __restrict__ bias,
               float* __restrict__ out_f,
               unsigned short* __restrict__ oa_hi, unsigned short* __restrict__ oa_lo,
               unsigned short* __restrict__ ob_hi, unsigned short* __restrict__ ob_lo)
{
    const int tid = threadIdx.x;
    const int wv = tid >> 6;
    const int quad = (tid >> 4) & 3;
    const int colk = tid & 15;
    const int m0 = blockIdx.x * 64;
    const int n0 = blockIdx.y * 64;

    __shared__ unsigned short wls_h[2][64][40];
    __shared__ unsigned short wls_l[2][64][40];

    const int sn = tid >> 2;
    const int sk = (tid & 3) * 8;
    const unsigned short* wsrc_h = w_hi + (size_t)(n0 + sn) * DD + sk;
    const unsigned short* wsrc_l = w_lo + (size_t)(n0 + sn) * DD + sk;

    const int am = min(m0 + wv * 16 + colk, NROWS - 1);
    const unsigned short *arh, *arl;
    if (MODE == 1) {
        if (am < 48) { arh = ms_hi + (size_t)am * DD; arl = ms_lo + (size_t)am * DD; }
        else         { arh = a_hi + (size_t)(am - 48) * DD; arl = a_lo + (size_t)(am - 48) * DD; }
    } else {
        arh = a_hi + (size_t)am * DD; arl = a_lo + (size_t)am * DD;
    }

    f32x4 acc[4] = {{0,0,0,0},{0,0,0,0},{0,0,0,0},{0,0,0,0}};

    // stage k-step 0 into buf 0
    {
        short8 sh = *(const short8*)(wsrc_h);
        short8 sl = *(const short8*)(wsrc_l);
        *(short8*)&wls_h[0][sn][sk] = sh;
        *(short8*)&wls_l[0][sn][sk] = sl;
    }
    __syncthreads();

    #pragma unroll 2
    for (int ks = 0; ks < 16; ++ks) {
        const int buf = ks & 1;
        const int k0 = ks * 32;
        // prefetch next W tile to regs (no barrier dependency)
        short8 nh, nl;
        if (ks + 1 < 16) {
            nh = *(const short8*)(wsrc_h + k0 + 32);
            nl = *(const short8*)(wsrc_l + k0 + 32);
        }
        short8 ah = *(const short8*)(arh + k0 + quad * 8);
        short8 al = *(const short8*)(arl + k0 + quad * 8);
        #pragma unroll
        for (int nt = 0; nt < 4; ++nt) {
            short8 bh = *(const short8*)&wls_h[buf][nt * 16 + colk][quad * 8];
            short8 bl = *(const short8*)&wls_l[buf][nt * 16 + colk][quad * 8];
            acc[nt] = __builtin_amdgcn_mfma_f32_16x16x32_bf16(ah, bh, acc[nt], 0, 0, 0);
            acc[nt] = __builtin_amdgcn_mfma_f32_16x16x32_bf16(ah, bl, acc[nt], 0, 0, 0);
            acc[nt] = __builtin_amdgcn_mfma_f32_16x16x32_bf16(al, bh, acc[nt], 0, 0, 0);
        }
        if (ks + 1 < 16) {
            *(short8*)&wls_h[buf ^ 1][sn][sk] = nh;
            *(short8*)&wls_l[buf ^ 1][sn][sk] = nl;
        }
        __syncthreads();
    }

    #pragma unroll
    for (int nt = 0; nt < 4; ++nt) {
        const int nn = n0 + nt * 16 + colk;
        const float bv = bias[nn];
        #pragma unroll
        for (int reg = 0; reg < 4; ++reg) {
            const int m = m0 + wv * 16 + quad * 4 + reg;
            if (m >= NROWS) continue;
            float v = acc[nt][reg] + bv;
            if (MODE == 0) {
                v *= 0.125f;
                int row = m >> 3, bb = m & 7, hh = nn >> 6, hd = nn & 63;
                size_t o = ((size_t)(bb * HH + hh) * TQ + row) * HDD + hd;
                unsigned short hi = f2bf(v);
                oa_hi[o] = hi; oa_lo[o] = f2bf(v - bf2f(hi));
            } else if (MODE == 1) {
                int row = m >> 3, bb = m & 7;
                if (nn < DD) {
                    int hh = nn >> 6, hd = nn & 63;
                    size_t o = ((size_t)(bb * HH + hh) * KLL + row) * HDD + hd;
                    unsigned short hi = f2bf(v);
                    oa_hi[o] = hi; oa_lo[o] = f2bf(v - bf2f(hi));
                } else {
                    int n2 = nn - DD;
                    int hh = n2 >> 6, hd = n2 & 63;
                    size_t o = ((size_t)(bb * HH + hh) * KLL + row) * HDD + hd;
                    unsigned short hi = f2bf(v);
                    ob_hi[o] = hi; ob_lo[o] = f2bf(v - bf2f(hi));
                }
            } else {
                int row = m >> 3;
                if (row >= TQ - MMEM) v = tanhf(v);
                out_f[(size_t)m * DD + nn] = v;
            }
        }
    }
}

// Attention: v14 EXACT (best measured: 263-274 us, five consistent runs).
__global__ __launch_bounds__(256, 3)
void attn_kernel(const unsigned short* __restrict__ qh_g,
                 const unsigned short* __restrict__ ql_g,
                 const unsigned short* __restrict__ kh_g,
                 const unsigned short* __restrict__ kl_g,
                 const unsigned short* __restrict__ vt_hi,
                 const unsigned short* __restrict__ vt_lo,
                 const int* __restrict__ lengths,
                 const unsigned int* __restrict__ pk2,
                 const unsigned short* __restrict__ rk_hi,
                 const unsigned short* __restrict__ rk_lo,
                 const float* __restrict__ rpe_v,
                 unsigned short* __restrict__ ao_hi,
                 unsigned short* __restrict__ ao_lo)
{
    // XCD-aware decode: xcd = id&7 fixed per head; t-chunks consecutive.
    const int id = blockIdx.x;
    const int xcd = id & 7;
    const int grp = id >> 3;             // 0..399
    const int t_chunk = grp % NTCH;
    const int n = (grp / NTCH) * 8 + xcd; // head index 0..63
    const int t0 = t_chunk * TB;
    const int rows = min(TB, TQ - t0);
    const int b = n >> 3;
    const int h = n & 7;
    const int tid = threadIdx.x;
    const int wv = tid >> 6;
    const int quad = (tid >> 4) & 3;
    const int colk = tid & 15;
    const int myk = wv * 16 + colk;

    __shared__ float qrk_l[TB][132];                 // qrk, then pr buckets (8448 B)
    __shared__ unsigned short p_hi[2][TB][72];       // 4608 B
    __shared__ unsigned short p_lo[2][TB][72];       // 4608 B
    __shared__ float4 stats_l[4][TB];                // 1024 B

    const int klen = lengths[b] + MMEM + RRCB;
    const int nch_live = (klen + CH - 1) / CH;       // block-uniform, 7..13
    const unsigned* pkg = pk2 + (size_t)t_chunk * 832 * 4;  // u32 units

#define LIVE(c) ((c) < MINCH || (c) < nch_live)

    // A fragments (Q), direct global, held all kernel. A row = query row colk.
    const int qrow = t0 + min(colk, rows - 1);
    const size_t qo = ((size_t)n * TQ + qrow) * HDD;
    short8 ah0 = *(const short8*)(qh_g + qo + quad * 8);
    short8 ah1 = *(const short8*)(qh_g + qo + 32 + quad * 8);
    short8 al0 = *(const short8*)(ql_g + qo + quad * 8);
    short8 al1 = *(const short8*)(ql_g + qo + 32 + quad * 8);

    // qrk via MFMA: wave wv does rpe_k row-tiles wv, wv+4, wv+8
    for (int t = wv; t < 9; t += 4) {
        const size_t rb = (size_t)(t * 16 + colk) * 64;
        short8 bh0 = *(const short8*)(rk_hi + rb + quad * 8);
        short8 bh1 = *(const short8*)(rk_hi + rb + 32 + quad * 8);
        short8 bl0 = *(const short8*)(rk_lo + rb + quad * 8);
        short8 bl1 = *(const short8*)(rk_lo + rb + 32 + quad * 8);
        f32x4 c4 = {0.f, 0.f, 0.f, 0.f};
        c4 = __builtin_amdgcn_mfma_f32_16x16x32_bf16(ah0, bh0, c4, 0, 0, 0);
        c4 = __builtin_amdgcn_mfma_f32_16x16x32_bf16(ah1, bh1, c4, 0, 0, 0);
        c4 = __builtin_amdgcn_mfma_f32_16x16x32_bf16(ah0, bl0, c4, 0, 0, 0);
        c4 = __builtin_amdgcn_mfma_f32_16x16x32_bf16(ah1, bl1, c4, 0, 0, 0);
        c4 = __builtin_amdgcn_mfma_f32_16x16x32_bf16(al0, bh0, c4, 0, 0, 0);
        c4 = __builtin_amdgcn_mfma_f32_16x16x32_bf16(al1, bh1, c4, 0, 0, 0);
        int c = t * 16 + colk;
        if (c <= 128) {
            #pragma unroll
            for (int reg = 0; reg < 4; ++reg) qrk_l[quad * 4 + reg][c] = c4[reg];
        }
    }
    __syncthreads();

    // ---- pass A: QK^T MFMA, record scores + max (live chunks only) ----
    float s_reg[NCH][4];
    float mx[4] = {-1e30f, -1e30f, -1e30f, -1e30f};

    #pragma unroll
    for (int cc = 0; cc < NCH; ++cc) {
        if (LIVE(cc)) {
            const int key = cc * CH + myk;
            const int krow = min(key, KLL - 1);
            const size_t ko = ((size_t)n * KLL + krow) * HDD;
            const unsigned r4 = pkg[key * 4 + quad];   // early: hides under MFMAs
            short8 bh0 = *(const short8*)(kh_g + ko + quad * 8);
            short8 bh1 = *(const short8*)(kh_g + ko + 32 + quad * 8);
            short8 bl0 = *(const short8*)(kl_g + ko + quad * 8);
            short8 bl1 = *(const short8*)(kl_g + ko + 32 + quad * 8);
            f32x4 c4a = {0.f, 0.f, 0.f, 0.f};
            f32x4 c4b = {0.f, 0.f, 0.f, 0.f};
            c4a = __builtin_amdgcn_mfma_f32_16x16x32_bf16(ah0, bh0, c4a, 0, 0, 0);
            c4b = __builtin_amdgcn_mfma_f32_16x16x32_bf16(ah1, bh1, c4b, 0, 0, 0);
            c4a = __builtin_amdgcn_mfma_f32_16x16x32_bf16(ah0, bl0, c4a, 0, 0, 0);
            c4b = __builtin_amdgcn_mfma_f32_16x16x32_bf16(ah1, bl1, c4b, 0, 0, 0);
            c4a = __builtin_amdgcn_mfma_f32_16x16x32_bf16(al0, bh0, c4a, 0, 0, 0);
            c4b = __builtin_amdgcn_mfma_f32_16x16x32_bf16(al1, bh1, c4b, 0, 0, 0);

            const bool vkey = (key < klen);
            #pragma unroll
            for (int reg = 0; reg < 4; ++reg) {
                const int row = quad * 4 + reg;
                const unsigned rid = (r4 >> (8 * reg)) & 255u;
                const float qv = qrk_l[row][min(rid, 128u)];   // clamped gather
                float s = (c4a[reg] + c4b[reg]) + qv;
                const bool ok = vkey && (row < rows) && (rid != 255u);
                s = ok ? s : -1e30f;
                mx[reg] = fmaxf(mx[reg], s);
                s_reg[cc][reg] = s;
            }
        } else {
            #pragma unroll
            for (int reg = 0; reg < 4; ++reg) s_reg[cc][reg] = -1e30f;
        }
    }

    // max merge: shfl16 then cross-wave
    #pragma unroll
    for (int reg = 0; reg < 4; ++reg)
        #pragma unroll
        for (int d = 1; d < 16; d <<= 1) mx[reg] = fmaxf(mx[reg], __shfl_xor(mx[reg], d, 16));
    if (colk == 0) {
        #pragma unroll
        for (int reg = 0; reg < 4; ++reg)
            stats_l[wv][quad * 4 + reg] = make_float4(mx[reg], 0.f, 0.f, 0.f);
    }
    __syncthreads();
    if (tid < TB) {
        float M = fmaxf(fmaxf(stats_l[0][tid].x, stats_l[1][tid].x),
                        fmaxf(stats_l[2][tid].x, stats_l[3][tid].x));
        stats_l[0][tid].x = M;
    }
    __syncthreads();

    // e-sweep (branchless): e = exp(s - M) (underflows to 0 for dead),
    // overwrite s_reg; accumulate l, l2, count (count via select).
    float Mr[4], l[4] = {0,0,0,0}, l2[4] = {0,0,0,0}, cn[4] = {0,0,0,0};
    #pragma unroll
    for (int reg = 0; reg < 4; ++reg) Mr[reg] = stats_l[0][quad * 4 + reg].x;
    #pragma unroll
    for (int cc = 0; cc < NCH; ++cc) {
        if (LIVE(cc)) {
            #pragma unroll
            for (int reg = 0; reg < 4; ++reg) {
                float s = s_reg[cc][reg];
                float e = expf(s - Mr[reg]);
                cn[reg] += (s > -1e29f) ? 1.f : 0.f;
                l[reg] += e;
                l2[reg] = fmaf(e, e, l2[reg]);
                s_reg[cc][reg] = e;
            }
        }
    }
    #pragma unroll
    for (int reg = 0; reg < 4; ++reg)
        #pragma unroll
        for (int d = 1; d < 16; d <<= 1) {
            l[reg]  += __shfl_xor(l[reg], d, 16);
            l2[reg] += __shfl_xor(l2[reg], d, 16);
            cn[reg] += __shfl_xor(cn[reg], d, 16);
        }
    if (colk == 0) {
        #pragma unroll
        for (int reg = 0; reg < 4; ++reg)
            stats_l[wv][quad * 4 + reg] = make_float4(Mr[reg], l[reg], l2[reg], cn[reg]);
    }
    __syncthreads();
    if (tid < TB) {
        float L = 0.f, L2 = 0.f, C = 0.f;
        #pragma unroll
        for (int w = 0; w < 4; ++w) {
            float4 s4 = stats_l[w][tid];
            L += s4.y; L2 += s4.z; C += s4.w;
        }
        float inv = (L > 0.f) ? 1.f / L : 0.f;
        float mean = 1.f / (C + 1e-8f);
        float sump2 = L2 * inv * inv;
        float var = (sump2 - 2.f * mean + C * mean * mean) / (C - 1.f + 1e-8f);
        var = fmaxf(var, 0.f);
        float thr = mean - 0.5f * sqrtf(var);
        stats_l[0][tid] = make_float4(stats_l[0][tid].x, inv, thr, 0.f);
    }
    // zero pr (qrk_l reuse; scores are stored, qrk dead after pass A)
    for (int i = tid; i < TB * 132; i += 256) ((float*)qrk_l)[i] = 0.f;
    __syncthreads();

    // ---- pass B: p = e*inv, threshold, buckets, PV via MFMA (live only) ----
    float inv_r[4], thr_r[4];
    #pragma unroll
    for (int reg = 0; reg < 4; ++reg) {
        float4 s4 = stats_l[0][quad * 4 + reg];
        inv_r[reg] = s4.y; thr_r[reg] = s4.z;
    }
    float sig[4] = {0.f, 0.f, 0.f, 0.f};
    f32x4 oaccA = {0.f, 0.f, 0.f, 0.f};
    f32x4 oaccB = {0.f, 0.f, 0.f, 0.f};

    auto computeP = [&](int cc, int buf, unsigned r4) {
        #pragma unroll
        for (int reg = 0; reg < 4; ++reg) {
            const int row = quad * 4 + reg;
            float p = s_reg[cc][reg] * inv_r[reg];
            if (p < thr_r[reg]) p = 0.f;
            sig[reg] += p;
            if (p > 0.f) {
                unsigned rid = (r4 >> (8 * reg)) & 255u;
                atomicAdd(&qrk_l[row][rid], p);
            }
            unsigned short ph = f2bf(p);
            p_hi[buf][row][myk] = ph;
            p_lo[buf][row][myk] = f2bf(p - bf2f(ph));
        }
    };

    // V fragment registers (current + prefetch handled per iteration)
    short8 vh0, vh1, vl0, vl1;
    {
        const size_t vbase = ((size_t)n * HDD + wv * 16 + colk) * VTS;
        vh0 = *(const short8*)(vt_hi + vbase + quad * 8);
        vh1 = *(const short8*)(vt_hi + vbase + 32 + quad * 8);
        vl0 = *(const short8*)(vt_lo + vbase + quad * 8);
        vl1 = *(const short8*)(vt_lo + vbase + 32 + quad * 8);
    }
    computeP(0, 0, pkg[myk * 4 + quad]);
    __syncthreads();
    #pragma unroll
    for (int cc = 0; cc < NCH; ++cc) {
        if (LIVE(cc)) {
            const bool nlive = (cc + 1 < NCH) && LIVE(cc + 1);
            // prefetch next chunk's V frags + pk word (global: no barrier dep)
            short8 nvh0, nvh1, nvl0, nvl1; unsigned nr4 = 0;
            if (nlive) {
                const size_t vbase = ((size_t)n * HDD + wv * 16 + colk) * VTS
                                   + (cc + 1) * CH;
                nvh0 = *(const short8*)(vt_hi + vbase + quad * 8);
                nvh1 = *(const short8*)(vt_hi + vbase + 32 + quad * 8);
                nvl0 = *(const short8*)(vt_lo + vbase + quad * 8);
                nvl1 = *(const short8*)(vt_lo + vbase + 32 + quad * 8);
                nr4 = pkg[((cc + 1) * CH + myk) * 4 + quad];
            }
            const int buf = cc & 1;
            short8 ph0 = *(const short8*)&p_hi[buf][colk][quad * 8];
            short8 ph1 = *(const short8*)&p_hi[buf][colk][32 + quad * 8];
            short8 pl0 = *(const short8*)&p_lo[buf][colk][quad * 8];
            short8 pl1 = *(const short8*)&p_lo[buf][colk][32 + quad * 8];
            oaccA = __builtin_amdgcn_mfma_f32_16x16x32_bf16(vh0, ph0, oaccA, 0, 0, 0);
            oaccB = __builtin_amdgcn_mfma_f32_16x16x32_bf16(vh1, ph1, oaccB, 0, 0, 0);
            oaccA = __builtin_amdgcn_mfma_f32_16x16x32_bf16(vh0, pl0, oaccA, 0, 0, 0);
            oaccB = __builtin_amdgcn_mfma_f32_16x16x32_bf16(vh1, pl1, oaccB, 0, 0, 0);
            oaccA = __builtin_amdgcn_mfma_f32_16x16x32_bf16(vl0, ph0, oaccA, 0, 0, 0);
            oaccB = __builtin_amdgcn_mfma_f32_16x16x32_bf16(vl1, ph1, oaccB, 0, 0, 0);
            if (nlive) computeP(cc + 1, (cc + 1) & 1, nr4);
            __syncthreads();
            if (nlive) { vh0 = nvh0; vh1 = nvh1; vl0 = nvl0; vl1 = nvl1; }
        }
    }

    // survivor-sum merge
    #pragma unroll
    for (int reg = 0; reg < 4; ++reg)
        #pragma unroll
        for (int d = 1; d < 16; d <<= 1) sig[reg] += __shfl_xor(sig[reg], d, 16);
    if (colk == 0) {
        #pragma unroll
        for (int reg = 0; reg < 4; ++reg)
            stats_l[wv][quad * 4 + reg].w = sig[reg];
    }
    __syncthreads();
    if (tid < TB) {
        float S = stats_l[0][tid].w + stats_l[1][tid].w + stats_l[2][tid].w + stats_l[3][tid].w;
        stats_l[0][tid].w = (S > 0.f) ? 1.f / S : 0.f;
    }
    __syncthreads();

    // output: lane owns O[row=colk][hd = wv*16 + quad*4 .. +3], bf16 hi/lo.
    // Branchless bucket dot: p == 0 contributes exactly 0, loads pipeline.
    if (colk < rows) {
        float4 ar = {0.f, 0.f, 0.f, 0.f};
        const int hdb = wv * 16 + quad * 4;
        #pragma unroll 4
        for (int c = 0; c < 129; ++c) {
            float p = qrk_l[colk][c];
            float4 v4 = *(const float4*)(rpe_v + (size_t)c * HDD + hdb);
            ar.x = fmaf(p, v4.x, ar.x);
            ar.y = fmaf(p, v4.y, ar.y);
            ar.z = fmaf(p, v4.z, ar.z);
            ar.w = fmaf(p, v4.w, ar.w);
        }
        const float invS = stats_l[0][colk].w;
        float o0 = (2.f * (oaccA[0] + oaccB[0]) + ar.x) * invS;
        float o1 = (2.f * (oaccA[1] + oaccB[1]) + ar.y) * invS;
        float o2 = (2.f * (oaccA[2] + oaccB[2]) + ar.z) * invS;
        float o3 = (2.f * (oaccA[3] + oaccB[3]) + ar.w) * invS;
        size_t oo = ((size_t)(t0 + colk) * BB + b) * DD + h * HDD + hdb;
        ushort4 oh, ol;
        oh.x = f2bf(o0); ol.x = f2bf(o0 - bf2f(oh.x));
        oh.y = f2bf(o1); ol.y = f2bf(o1 - bf2f(oh.y));
        oh.z = f2bf(o2); ol.z = f2bf(o2 - bf2f(oh.z));
        oh.w = f2bf(o3); ol.w = f2bf(o3 - bf2f(oh.w));
        *(ushort4*)(ao_hi + oo) = oh;
        *(ushort4*)(ao_lo + oo) = ol;
    }
#undef LIVE
}

extern "C" void kernel_launch(void* const* d_in, const int* in_sizes, int n_in,
                              void* d_out, int out_size, void* d_ws, size_t ws_size,
                              hipStream_t stream) {
    const float*          x      = (const float*)d_in[0];
    const int*            lengths= (const int*)d_in[1];
    const float*          mems   = (const float*)d_in[2];
    const void*           amask  = (const void*)d_in[3];
    const int*            rpe    = (const int*)d_in[4];
    const float*          wq     = (const float*)d_in[6];
    const float*          bq     = (const float*)d_in[7];
    const float*          wkv    = (const float*)d_in[8];
    const float*          bkv    = (const float*)d_in[9];
    const float*          wo     = (const float*)d_in[10];
    const float*          bo     = (const float*)d_in[11];
    const float*          rpe_k  = (const float*)d_in[12];
    const float*          rpe_v  = (const float*)d_in[13];

    const size_t NE = (size_t)NROWS * DD;           // 3,268,608
    const size_t VTN = (size_t)NHEADS * HDD * VTS;  // 3,407,872

    char* p = (char*)d_ws;
    unsigned short* q_hi = (unsigned short*)p;  p += NE * 2;
    unsigned short* q_lo = (unsigned short*)p;  p += NE * 2;
    // union region: xs/ms (proj inputs, dead after proj) | vt (written after)
    char* uni = p;                              p += VTN * 4;   // vt is the larger
    unsigned short* xs_hi = (unsigned short*)uni;
    unsigned short* xs_lo = xs_hi + NE;
    unsigned short* ms_hi = xs_lo + NE;
    unsigned short* ms_lo = ms_hi + 48 * DD;
    unsigned short* vt_hi = (unsigned short*)uni;
    unsigned short* vt_lo = vt_hi + VTN;
    unsigned short* w_hi = (unsigned short*)p;  p += (size_t)2048 * DD * 2;
    unsigned short* w_lo = (unsigned short*)p;  p += (size_t)2048 * DD * 2;
    unsigned short* k_hi = (unsigned short*)p;  p += NE * 2;
    unsigned short* k_lo = (unsigned short*)p;  p += NE * 2;
    unsigned short* vr_hi = (unsigned short*)p; p += NE * 2;   // aliased by ao after transpose
    unsigned short* vr_lo = (unsigned short*)p; p += NE * 2;
    unsigned short* ao_hi = vr_hi;
    unsigned short* ao_lo = vr_lo;
    unsigned short* rk_hi = (unsigned short*)p; p += 144 * 64 * 2;
    unsigned short* rk_lo = (unsigned short*)p; p += 144 * 64 * 2;
    unsigned int*   pk2   = (unsigned int*)p;   p += (size_t)NTCH * 832 * 16;

    {
        const size_t sp_total = NE + (size_t)48 * DD + (size_t)2048 * DD;  // 4,341,760
        const int sp_blocks = (int)((sp_total + 1023) / 1024);             // 4,240
        prep_kernel<<<PK2_BLOCKS + RK_BLOCKS + sp_blocks, 256, 0, stream>>>(
            amask, rpe, pk2,
            rpe_k, rk_hi, rk_lo,
            x, mems, wq, wkv, wo,
            xs_hi, xs_lo, ms_hi, ms_lo, w_hi, w_lo);
    }
    mfma_proj<0><<<dim3(100, 8), 256, 0, stream>>>(
        xs_hi, xs_lo, nullptr, nullptr, w_hi, w_lo, bq,
        nullptr, q_hi, q_lo, nullptr, nullptr);
    mfma_proj<1><<<dim3(100, 16), 256, 0, stream>>>(
        xs_hi, xs_lo, ms_hi, ms_lo, w_hi + (size_t)512 * DD, w_lo + (size_t)512 * DD, bkv,
        nullptr, k_hi, k_lo, vr_hi, vr_lo);
    transpose_v_kernel<<<dim3(13, NHEADS), 256, 0, stream>>>(vr_hi, vr_lo, vt_hi, vt_lo);
    attn_kernel<<<3200, 256, 0, stream>>>(
        q_hi, q_lo, k_hi, k_lo, vt_hi, vt_lo, lengths, pk2, rk_hi, rk_lo, rpe_v, ao_hi, ao_lo);
    mfma_proj<2><<<dim3(100, 8), 256, 0, stream>>>(
        ao_hi, ao_lo, nullptr, nullptr, w_hi + (size_t)1536 * DD, w_lo + (size_t)1536 * DD, bo,
        (float*)d_out, nullptr, nullptr, nullptr, nullptr);
}

// Round 12
// 454.350 us; speedup vs baseline: 1.0735x; 1.0030x over previous
//
#include <hip/hip_runtime.h>
#include <hip/hip_bf16.h>
#include <math.h>

// Problem constants (fixed by the reference)
#define TT   799
#define BB   8
#define DD   512
#define HH   8
#define HDD  64
#define MMEM 6
#define RRCB 24
#define KLL  798
#define TQ   798            // query rows actually needed (row 798 unused)
#define NROWS (TQ * BB)     // 6384
#define NHEADS 64           // B*H
#define NEG_INF (-INFINITY)

#define TB   16             // t-rows per attention block
#define CH   64             // keys per MFMA chunk
#define NCH  13             // 13*64 = 832 >= 798
#define VTS  832            // v_t row stride in keys
#define NTCH 50             // t-chunks (50*16 = 800 >= TQ)
#define MINCH 7             // klen >= 430 always -> chunks 0..6 always live

static_assert(NROWS == 6384, "");

typedef __attribute__((ext_vector_type(8))) short short8;
typedef __attribute__((ext_vector_type(4))) float f32x4;

__device__ __forceinline__ unsigned short f2bf(float x) {
    union { float f; unsigned u; } c; c.f = x;
    unsigned r = c.u + 0x7FFFu + ((c.u >> 16) & 1u);   // RNE
    return (unsigned short)(r >> 16);
}
__device__ __forceinline__ float bf2f(unsigned short b) {
    union { unsigned u; float f; } c; c.u = ((unsigned)b) << 16; return c.f;
}

// Fused prep: transposed (mask,rpe)->rid pack pk2[t_chunk][key][row] |
// rpe_k hi/lo split | x/mems/W hi/lo split (float4-vectorized).
// Mask dtype (mode 0 = int32 0/1, 1 = float32, 2 = uint8) is detected
// IN-BLOCK from the first 4096 mask words (16KB, L2-hot, deterministic,
// block-uniform). v17 lesson: dtype MUST come from device data.
#define RK_BLOCKS 36
#define PK2_BLOCKS (NTCH * 13)   // 650: one block per (t_chunk, 64-key group)
__global__ __launch_bounds__(256)
void prep_kernel(const void* __restrict__ amask,
                 const int* __restrict__ rpe,
                 unsigned int* __restrict__ pk2,
                 const float* __restrict__ rpe_k,
                 unsigned short* __restrict__ rk_hi,
                 unsigned short* __restrict__ rk_lo,
                 const float* __restrict__ x,
                 const float* __restrict__ mems,
                 const float* __restrict__ wq,
                 const float* __restrict__ wkv,
                 const float* __restrict__ wo,
                 unsigned short* __restrict__ xs_hi, unsigned short* __restrict__ xs_lo,
                 unsigned short* __restrict__ ms_hi, unsigned short* __restrict__ ms_lo,
                 unsigned short* __restrict__ w_hi,  unsigned short* __restrict__ w_lo)
{
    const int bid = blockIdx.x;
    const int tid = threadIdx.x;
    if (bid < PK2_BLOCKS) {
        // in-block mask-dtype detection (identical result in every block)
        __shared__ int c0s, cHs;
        if (tid == 0) { c0s = 0; cHs = 0; }
        __syncthreads();
        {
            int c0 = 0, cH = 0;
            const unsigned* aw = (const unsigned*)amask;
            for (int i = tid; i < 4096; i += 256) {
                unsigned w = aw[i];
                if (w & 0x000000FFu) c0++;
                if (w & 0xFFFFFF00u) cH++;
            }
            atomicAdd(&c0s, c0); atomicAdd(&cHs, cH);
        }
        __syncthreads();
        const int mode = (cHs == 0) ? 0 : ((c0s == 0) ? 1 : 2);

        // transposed rid pack: byte (chunk, key, row) = rid or 255.
        const int chunk = bid / 13;
        const int kg = bid - chunk * 13;
        const int k64 = tid >> 2;          // 0..63
        const int word = tid & 3;          // covers rows word*4 .. word*4+3
        const int key = kg * 64 + k64;     // 0..831
        unsigned out = 0;
        #pragma unroll
        for (int r = 0; r < 4; ++r) {
            const int row = word * 4 + r;
            const int t = chunk * 16 + row;    // 0..799
            unsigned byte = 255u;
            if (key < KLL && t < TT) {
                size_t idx = (size_t)t * KLL + key;
                bool masked;
                if (mode == 0)      masked = (((const int*)amask)[idx] != 0);
                else if (mode == 1) masked = (((const float*)amask)[idx] != 0.f);
                else                masked = (((const unsigned char*)amask)[idx] != 0);
                byte = masked ? 255u : (unsigned)rpe[idx];
            }
            out |= byte << (8 * r);
        }
        pk2[((size_t)chunk * 832 + key) * 4 + word] = out;
    } else if (bid < PK2_BLOCKS + RK_BLOCKS) {
        int i = (bid - PK2_BLOCKS) * 256 + tid;
        if (i >= 144 * 64) return;
        int c = i >> 6;
        float v = (c < 129) ? rpe_k[i] : 0.f;
        unsigned short hi = f2bf(v);
        rk_hi[i] = hi;
        rk_lo[i] = f2bf(v - bf2f(hi));
    } else {
        // hi/lo split, 4 elements/thread (regions are all multiples of 4).
        const size_t NX = (size_t)NROWS * DD;
        const size_t NM = 48 * DD;
        const size_t NW = 2048 * DD;
        size_t i = ((size_t)(bid - PK2_BLOCKS - RK_BLOCKS) * 256 + tid) * 4;
        float4 v4; unsigned short *dh, *dl; size_t o;
        if (i < NX) { o = i; v4 = *(const float4*)(x + o); dh = xs_hi; dl = xs_lo; }
        else if (i < NX + NM) { o = i - NX; v4 = *(const float4*)(mems + o); dh = ms_hi; dl = ms_lo; }
        else if (i < NX + NM + NW) {
            o = i - NX - NM;
            size_t r = o >> 9;
            if (r < 512)       v4 = *(const float4*)(wq + o);
            else if (r < 1536) v4 = *(const float4*)(wkv + (o - (size_t)512 * DD));
            else               v4 = *(const float4*)(wo + (o - (size_t)1536 * DD));
            dh = w_hi; dl = w_lo;
        } else return;
        ushort4 h, lo;
        h.x = f2bf(v4.x); lo.x = f2bf(v4.x - bf2f(h.x));
        h.y = f2bf(v4.y); lo.y = f2bf(v4.y - bf2f(h.y));
        h.z = f2bf(v4.z); lo.z = f2bf(v4.z - bf2f(h.z));
        h.w = f2bf(v4.w); lo.w = f2bf(v4.w - bf2f(h.w));
        *(ushort4*)(dh + o) = h;
        *(ushort4*)(dl + o) = lo;
    }
}

// v row-major bf16 hi/lo [head][key][hd] -> v_t [head][hd][VTS] (keys 798..831 zero)
__global__ __launch_bounds__(256)
void transpose_v_kernel(const unsigned short* __restrict__ vr_hi,
                        const unsigned short* __restrict__ vr_lo,
                        unsigned short* __restrict__ vt_hi,
                        unsigned short* __restrict__ vt_lo)
{
    const int head = blockIdx.y;
    const int kb = blockIdx.x * 64;
    __shared__ unsigned short th[64][66];
    __shared__ unsigned short tl[64][66];
    const int tid = threadIdx.x;
    for (int i = tid; i < 64 * 64; i += 256) {
        int ky = i >> 6, hd = i & 63;
        int key = kb + ky;
        unsigned short hv = 0, lv = 0;
        if (key < KLL) {
            size_t o = ((size_t)head * KLL + key) * HDD + hd;
            hv = vr_hi[o]; lv = vr_lo[o];
        }
        th[ky][hd] = hv; tl[ky][hd] = lv;
    }
    __syncthreads();
    for (int i = tid; i < 64 * 64; i += 256) {
        int hd = i >> 6, ky = i & 63;
        size_t o = ((size_t)head * HDD + hd) * VTS + kb + ky;
        vt_hi[o] = th[ky][hd];
        vt_lo[o] = tl[ky][hd];
    }
}

// MFMA GEMM v2: LDS-staged W (v16's proven scheme). 64n x 32k W tile
// (hi+lo) staged to LDS once per k-step (reg-staged, double-buffered,
// 40-short padded rows); all 4 waves read frags via ds_read_b128.
// MODE 0: A = xs, out q hi/lo (scaled 0.125). MODE 1: A = mem_rc (ms|xs),
// out k hi/lo (n<512) or vr hi/lo. MODE 2: A = ao, out f32 (+tanh tail rows).
template<int MODE>
__global__ __launch_bounds__(256, 4)
void mfma_proj(const unsigned short* __restrict__ a_hi,
               const unsigned short* __restrict__ a_lo,
               const unsigned short* __restrict__ ms_hi,
               const unsigned short* __restrict__ ms_lo,
               const unsigned short* __restrict__ w_hi,
               const unsigned short* __restrict__ w_lo,
               const float* __restrict__ bias,
               float* __restrict__ out_f,
               unsigned short* __restrict__ oa_hi, unsigned short* __restrict__ oa_lo,
               unsigned short* __restrict__ ob_hi, unsigned short* __restrict__ ob_lo)
{
    const int tid = threadIdx.x;
    const int wv = tid >> 6;
    const int quad = (tid >> 4) & 3;
    const int colk = tid & 15;
    const int m0 = blockIdx.x * 64;
    const int n0 = blockIdx.y * 64;

    __shared__ unsigned short wls_h[2][64][40];
    __shared__ unsigned short wls_l[2][64][40];

    const int sn = tid >> 2;
    const int sk = (tid & 3) * 8;
    const unsigned short* wsrc_h = w_hi + (size_t)(n0 + sn) * DD + sk;
    const unsigned short* wsrc_l = w_lo + (size_t)(n0 + sn) * DD + sk;

    const int am = min(m0 + wv * 16 + colk, NROWS - 1);
    const unsigned short *arh, *arl;
    if (MODE == 1) {
        if (am < 48) { arh = ms_hi + (size_t)am * DD; arl = ms_lo + (size_t)am * DD; }
        else         { arh = a_hi + (size_t)(am - 48) * DD; arl = a_lo + (size_t)(am - 48) * DD; }
    } else {
        arh = a_hi + (size_t)am * DD; arl = a_lo + (size_t)am * DD;
    }

    f32x4 acc[4] = {{0,0,0,0},{0,0,0,0},{0,0,0,0},{0,0,0,0}};

    // stage k-step 0 into buf 0
    {
        short8 sh = *(const short8*)(wsrc_h);
        short8 sl = *(const short8*)(wsrc_l);
        *(short8*)&wls_h[0][sn][sk] = sh;
        *(short8*)&wls_l[0][sn][sk] = sl;
    }
    __syncthreads();

    #pragma unroll 2
    for (int ks = 0; ks < 16; ++ks) {
        const int buf = ks & 1;
        const int k0 = ks * 32;
        // prefetch next W tile to regs (no barrier dependency)
        short8 nh, nl;
        if (ks + 1 < 16) {
            nh = *(const short8*)(wsrc_h + k0 + 32);
            nl = *(const short8*)(wsrc_l + k0 + 32);
        }
        short8 ah = *(const short8*)(arh + k0 + quad * 8);
        short8 al = *(const short8*)(arl + k0 + quad * 8);
        #pragma unroll
        for (int nt = 0; nt < 4; ++nt) {
            short8 bh = *(const short8*)&wls_h[buf][nt * 16 + colk][quad * 8];
            short8 bl = *(const short8*)&wls_l[buf][nt * 16 + colk][quad * 8];
            acc[nt] = __builtin_amdgcn_mfma_f32_16x16x32_bf16(ah, bh, acc[nt], 0, 0, 0);
            acc[nt] = __builtin_amdgcn_mfma_f32_16x16x32_bf16(ah, bl, acc[nt], 0, 0, 0);
            acc[nt] = __builtin_amdgcn_mfma_f32_16x16x32_bf16(al, bh, acc[nt], 0, 0, 0);
        }
        if (ks + 1 < 16) {
            *(short8*)&wls_h[buf ^ 1][sn][sk] = nh;
            *(short8*)&wls_l[buf ^ 1][sn][sk] = nl;
        }
        __syncthreads();
    }

    #pragma unroll
    for (int nt = 0; nt < 4; ++nt) {
        const int nn = n0 + nt * 16 + colk;
        const float bv = bias[nn];
        #pragma unroll
        for (int reg = 0; reg < 4; ++reg) {
            const int m = m0 + wv * 16 + quad * 4 + reg;
            if (m >= NROWS) continue;
            float v = acc[nt][reg] + bv;
            if (MODE == 0) {
                v *= 0.125f;
                int row = m >> 3, bb = m & 7, hh = nn >> 6, hd = nn & 63;
                size_t o = ((size_t)(bb * HH + hh) * TQ + row) * HDD + hd;
                unsigned short hi = f2bf(v);
                oa_hi[o] = hi; oa_lo[o] = f2bf(v - bf2f(hi));
            } else if (MODE == 1) {
                int row = m >> 3, bb = m & 7;
                if (nn < DD) {
                    int hh = nn >> 6, hd = nn & 63;
                    size_t o = ((size_t)(bb * HH + hh) * KLL + row) * HDD + hd;
                    unsigned short hi = f2bf(v);
                    oa_hi[o] = hi; oa_lo[o] = f2bf(v - bf2f(hi));
                } else {
                    int n2 = nn - DD;
                    int hh = n2 >> 6, hd = n2 & 63;
                    size_t o = ((size_t)(bb * HH + hh) * KLL + row) * HDD + hd;
                    unsigned short hi = f2bf(v);
                    ob_hi[o] = hi; ob_lo[o] = f2bf(v - bf2f(hi));
                }
            } else {
                int row = m >> 3;
                if (row >= TQ - MMEM) v = tanhf(v);
                out_f[(size_t)m * DD + nn] = v;
            }
        }
    }
}

// Attention: v14 numerics EXACT + s_setprio(1) around MFMA clusters (T5).
// Mechanism (learn_hip m191): independent blocks at different phases on a
// CU -> raising priority during MFMA chains keeps the matrix pipe fed
// instead of round-robining into load-stalled waves. Null on lockstep
// GEMM (m190) -> projs untouched.
__global__ __launch_bounds__(256, 3)
void attn_kernel(const unsigned short* __restrict__ qh_g,
                 const unsigned short* __restrict__ ql_g,
                 const unsigned short* __restrict__ kh_g,
                 const unsigned short* __restrict__ kl_g,
                 const unsigned short* __restrict__ vt_hi,
                 const unsigned short* __restrict__ vt_lo,
                 const int* __restrict__ lengths,
                 const unsigned int* __restrict__ pk2,
                 const unsigned short* __restrict__ rk_hi,
                 const unsigned short* __restrict__ rk_lo,
                 const float* __restrict__ rpe_v,
                 unsigned short* __restrict__ ao_hi,
                 unsigned short* __restrict__ ao_lo)
{
    // XCD-aware decode: xcd = id&7 fixed per head; t-chunks consecutive.
    const int id = blockIdx.x;
    const int xcd = id & 7;
    const int grp = id >> 3;             // 0..399
    const int t_chunk = grp % NTCH;
    const int n = (grp / NTCH) * 8 + xcd; // head index 0..63
    const int t0 = t_chunk * TB;
    const int rows = min(TB, TQ - t0);
    const int b = n >> 3;
    const int h = n & 7;
    const int tid = threadIdx.x;
    const int wv = tid >> 6;
    const int quad = (tid >> 4) & 3;
    const int colk = tid & 15;
    const int myk = wv * 16 + colk;

    __shared__ float qrk_l[TB][132];                 // qrk, then pr buckets (8448 B)
    __shared__ unsigned short p_hi[2][TB][72];       // 4608 B
    __shared__ unsigned short p_lo[2][TB][72];       // 4608 B
    __shared__ float4 stats_l[4][TB];                // 1024 B

    const int klen = lengths[b] + MMEM + RRCB;
    const int nch_live = (klen + CH - 1) / CH;       // block-uniform, 7..13
    const unsigned* pkg = pk2 + (size_t)t_chunk * 832 * 4;  // u32 units

#define LIVE(c) ((c) < MINCH || (c) < nch_live)

    // A fragments (Q), direct global, held all kernel. A row = query row colk.
    const int qrow = t0 + min(colk, rows - 1);
    const size_t qo = ((size_t)n * TQ + qrow) * HDD;
    short8 ah0 = *(const short8*)(qh_g + qo + quad * 8);
    short8 ah1 = *(const short8*)(qh_g + qo + 32 + quad * 8);
    short8 al0 = *(const short8*)(ql_g + qo + quad * 8);
    short8 al1 = *(const short8*)(ql_g + qo + 32 + quad * 8);

    // qrk via MFMA: wave wv does rpe_k row-tiles wv, wv+4, wv+8
    for (int t = wv; t < 9; t += 4) {
        const size_t rb = (size_t)(t * 16 + colk) * 64;
        short8 bh0 = *(const short8*)(rk_hi + rb + quad * 8);
        short8 bh1 = *(const short8*)(rk_hi + rb + 32 + quad * 8);
        short8 bl0 = *(const short8*)(rk_lo + rb + quad * 8);
        short8 bl1 = *(const short8*)(rk_lo + rb + 32 + quad * 8);
        f32x4 c4 = {0.f, 0.f, 0.f, 0.f};
        __builtin_amdgcn_s_setprio(1);
        c4 = __builtin_amdgcn_mfma_f32_16x16x32_bf16(ah0, bh0, c4, 0, 0, 0);
        c4 = __builtin_amdgcn_mfma_f32_16x16x32_bf16(ah1, bh1, c4, 0, 0, 0);
        c4 = __builtin_amdgcn_mfma_f32_16x16x32_bf16(ah0, bl0, c4, 0, 0, 0);
        c4 = __builtin_amdgcn_mfma_f32_16x16x32_bf16(ah1, bl1, c4, 0, 0, 0);
        c4 = __builtin_amdgcn_mfma_f32_16x16x32_bf16(al0, bh0, c4, 0, 0, 0);
        c4 = __builtin_amdgcn_mfma_f32_16x16x32_bf16(al1, bh1, c4, 0, 0, 0);
        __builtin_amdgcn_s_setprio(0);
        int c = t * 16 + colk;
        if (c <= 128) {
            #pragma unroll
            for (int reg = 0; reg < 4; ++reg) qrk_l[quad * 4 + reg][c] = c4[reg];
        }
    }
    __syncthreads();

    // ---- pass A: QK^T MFMA, record scores + max (live chunks only) ----
    float s_reg[NCH][4];
    float mx[4] = {-1e30f, -1e30f, -1e30f, -1e30f};

    #pragma unroll
    for (int cc = 0; cc < NCH; ++cc) {
        if (LIVE(cc)) {
            const int key = cc * CH + myk;
            const int krow = min(key, KLL - 1);
            const size_t ko = ((size_t)n * KLL + krow) * HDD;
            const unsigned r4 = pkg[key * 4 + quad];   // early: hides under MFMAs
            short8 bh0 = *(const short8*)(kh_g + ko + quad * 8);
            short8 bh1 = *(const short8*)(kh_g + ko + 32 + quad * 8);
            short8 bl0 = *(const short8*)(kl_g + ko + quad * 8);
            short8 bl1 = *(const short8*)(kl_g + ko + 32 + quad * 8);
            f32x4 c4a = {0.f, 0.f, 0.f, 0.f};
            f32x4 c4b = {0.f, 0.f, 0.f, 0.f};
            __builtin_amdgcn_s_setprio(1);
            c4a = __builtin_amdgcn_mfma_f32_16x16x32_bf16(ah0, bh0, c4a, 0, 0, 0);
            c4b = __builtin_amdgcn_mfma_f32_16x16x32_bf16(ah1, bh1, c4b, 0, 0, 0);
            c4a = __builtin_amdgcn_mfma_f32_16x16x32_bf16(ah0, bl0, c4a, 0, 0, 0);
            c4b = __builtin_amdgcn_mfma_f32_16x16x32_bf16(ah1, bl1, c4b, 0, 0, 0);
            c4a = __builtin_amdgcn_mfma_f32_16x16x32_bf16(al0, bh0, c4a, 0, 0, 0);
            c4b = __builtin_amdgcn_mfma_f32_16x16x32_bf16(al1, bh1, c4b, 0, 0, 0);
            __builtin_amdgcn_s_setprio(0);

            const bool vkey = (key < klen);
            #pragma unroll
            for (int reg = 0; reg < 4; ++reg) {
                const int row = quad * 4 + reg;
                const unsigned rid = (r4 >> (8 * reg)) & 255u;
                const float qv = qrk_l[row][min(rid, 128u)];   // clamped gather
                float s = (c4a[reg] + c4b[reg]) + qv;
                const bool ok = vkey && (row < rows) && (rid != 255u);
                s = ok ? s : -1e30f;
                mx[reg] = fmaxf(mx[reg], s);
                s_reg[cc][reg] = s;
            }
        } else {
            #pragma unroll
            for (int reg = 0; reg < 4; ++reg) s_reg[cc][reg] = -1e30f;
        }
    }

    // max merge: shfl16 then cross-wave
    #pragma unroll
    for (int reg = 0; reg < 4; ++reg)
        #pragma unroll
        for (int d = 1; d < 16; d <<= 1) mx[reg] = fmaxf(mx[reg], __shfl_xor(mx[reg], d, 16));
    if (colk == 0) {
        #pragma unroll
        for (int reg = 0; reg < 4; ++reg)
            stats_l[wv][quad * 4 + reg] = make_float4(mx[reg], 0.f, 0.f, 0.f);
    }
    __syncthreads();
    if (tid < TB) {
        float M = fmaxf(fmaxf(stats_l[0][tid].x, stats_l[1][tid].x),
                        fmaxf(stats_l[2][tid].x, stats_l[3][tid].x));
        stats_l[0][tid].x = M;
    }
    __syncthreads();

    // e-sweep (branchless): e = exp(s - M) (underflows to 0 for dead),
    // overwrite s_reg; accumulate l, l2, count (count via select).
    float Mr[4], l[4] = {0,0,0,0}, l2[4] = {0,0,0,0}, cn[4] = {0,0,0,0};
    #pragma unroll
    for (int reg = 0; reg < 4; ++reg) Mr[reg] = stats_l[0][quad * 4 + reg].x;
    #pragma unroll
    for (int cc = 0; cc < NCH; ++cc) {
        if (LIVE(cc)) {
            #pragma unroll
            for (int reg = 0; reg < 4; ++reg) {
                float s = s_reg[cc][reg];
                float e = expf(s - Mr[reg]);
                cn[reg] += (s > -1e29f) ? 1.f : 0.f;
                l[reg] += e;
                l2[reg] = fmaf(e, e, l2[reg]);
                s_reg[cc][reg] = e;
            }
        }
    }
    #pragma unroll
    for (int reg = 0; reg < 4; ++reg)
        #pragma unroll
        for (int d = 1; d < 16; d <<= 1) {
            l[reg]  += __shfl_xor(l[reg], d, 16);
            l2[reg] += __shfl_xor(l2[reg], d, 16);
            cn[reg] += __shfl_xor(cn[reg], d, 16);
        }
    if (colk == 0) {
        #pragma unroll
        for (int reg = 0; reg < 4; ++reg)
            stats_l[wv][quad * 4 + reg] = make_float4(Mr[reg], l[reg], l2[reg], cn[reg]);
    }
    __syncthreads();
    if (tid < TB) {
        float L = 0.f, L2 = 0.f, C = 0.f;
        #pragma unroll
        for (int w = 0; w < 4; ++w) {
            float4 s4 = stats_l[w][tid];
            L += s4.y; L2 += s4.z; C += s4.w;
        }
        float inv = (L > 0.f) ? 1.f / L : 0.f;
        float mean = 1.f / (C + 1e-8f);
        float sump2 = L2 * inv * inv;
        float var = (sump2 - 2.f * mean + C * mean * mean) / (C - 1.f + 1e-8f);
        var = fmaxf(var, 0.f);
        float thr = mean - 0.5f * sqrtf(var);
        stats_l[0][tid] = make_float4(stats_l[0][tid].x, inv, thr, 0.f);
    }
    // zero pr (qrk_l reuse; scores are stored, qrk dead after pass A)
    for (int i = tid; i < TB * 132; i += 256) ((float*)qrk_l)[i] = 0.f;
    __syncthreads();

    // ---- pass B: p = e*inv, threshold, buckets, PV via MFMA (live only) ----
    float inv_r[4], thr_r[4];
    #pragma unroll
    for (int reg = 0; reg < 4; ++reg) {
        float4 s4 = stats_l[0][quad * 4 + reg];
        inv_r[reg] = s4.y; thr_r[reg] = s4.z;
    }
    float sig[4] = {0.f, 0.f, 0.f, 0.f};
    f32x4 oaccA = {0.f, 0.f, 0.f, 0.f};
    f32x4 oaccB = {0.f, 0.f, 0.f, 0.f};

    auto computeP = [&](int cc, int buf, unsigned r4) {
        #pragma unroll
        for (int reg = 0; reg < 4; ++reg) {
            const int row = quad * 4 + reg;
            float p = s_reg[cc][reg] * inv_r[reg];
            if (p < thr_r[reg]) p = 0.f;
            sig[reg] += p;
            if (p > 0.f) {
                unsigned rid = (r4 >> (8 * reg)) & 255u;
                atomicAdd(&qrk_l[row][rid], p);
            }
            unsigned short ph = f2bf(p);
            p_hi[buf][row][myk] = ph;
            p_lo[buf][row][myk] = f2bf(p - bf2f(ph));
        }
    };

    // V fragment registers (current + prefetch handled per iteration)
    short8 vh0, vh1, vl0, vl1;
    {
        const size_t vbase = ((size_t)n * HDD + wv * 16 + colk) * VTS;
        vh0 = *(const short8*)(vt_hi + vbase + quad * 8);
        vh1 = *(const short8*)(vt_hi + vbase + 32 + quad * 8);
        vl0 = *(const short8*)(vt_lo + vbase + quad * 8);
        vl1 = *(const short8*)(vt_lo + vbase + 32 + quad * 8);
    }
    computeP(0, 0, pkg[myk * 4 + quad]);
    __syncthreads();
    #pragma unroll
    for (int cc = 0; cc < NCH; ++cc) {
        if (LIVE(cc)) {
            const bool nlive = (cc + 1 < NCH) && LIVE(cc + 1);
            // prefetch next chunk's V frags + pk word (global: no barrier dep)
            short8 nvh0, nvh1, nvl0, nvl1; unsigned nr4 = 0;
            if (nlive) {
                const size_t vbase = ((size_t)n * HDD + wv * 16 + colk) * VTS
                                   + (cc + 1) * CH;
                nvh0 = *(const short8*)(vt_hi + vbase + quad * 8);
                nvh1 = *(const short8*)(vt_hi + vbase + 32 + quad * 8);
                nvl0 = *(const short8*)(vt_lo + vbase + quad * 8);
                nvl1 = *(const short8*)(vt_lo + vbase + 32 + quad * 8);
                nr4 = pkg[((cc + 1) * CH + myk) * 4 + quad];
            }
            const int buf = cc & 1;
            short8 ph0 = *(const short8*)&p_hi[buf][colk][quad * 8];
            short8 ph1 = *(const short8*)&p_hi[buf][colk][32 + quad * 8];
            short8 pl0 = *(const short8*)&p_lo[buf][colk][quad * 8];
            short8 pl1 = *(const short8*)&p_lo[buf][colk][32 + quad * 8];
            __builtin_amdgcn_s_setprio(1);
            oaccA = __builtin_amdgcn_mfma_f32_16x16x32_bf16(vh0, ph0, oaccA, 0, 0, 0);
            oaccB = __builtin_amdgcn_mfma_f32_16x16x32_bf16(vh1, ph1, oaccB, 0, 0, 0);
            oaccA = __builtin_amdgcn_mfma_f32_16x16x32_bf16(vh0, pl0, oaccA, 0, 0, 0);
            oaccB = __builtin_amdgcn_mfma_f32_16x16x32_bf16(vh1, pl1, oaccB, 0, 0, 0);
            oaccA = __builtin_amdgcn_mfma_f32_16x16x32_bf16(vl0, ph0, oaccA, 0, 0, 0);
            oaccB = __builtin_amdgcn_mfma_f32_16x16x32_bf16(vl1, ph1, oaccB, 0, 0, 0);
            __builtin_amdgcn_s_setprio(0);
            if (nlive) computeP(cc + 1, (cc + 1) & 1, nr4);
            __syncthreads();
            if (nlive) { vh0 = nvh0; vh1 = nvh1; vl0 = nvl0; vl1 = nvl1; }
        }
    }

    // survivor-sum merge
    #pragma unroll
    for (int reg = 0; reg < 4; ++reg)
        #pragma unroll
        for (int d = 1; d < 16; d <<= 1) sig[reg] += __shfl_xor(sig[reg], d, 16);
    if (colk == 0) {
        #pragma unroll
        for (int reg = 0; reg < 4; ++reg)
            stats_l[wv][quad * 4 + reg].w = sig[reg];
    }
    __syncthreads();
    if (tid < TB) {
        float S = stats_l[0][tid].w + stats_l[1][tid].w + stats_l[2][tid].w + stats_l[3][tid].w;
        stats_l[0][tid].w = (S > 0.f) ? 1.f / S : 0.f;
    }
    __syncthreads();

    // output: lane owns O[row=colk][hd = wv*16 + quad*4 .. +3], bf16 hi/lo.
    // Branchless bucket dot: p == 0 contributes exactly 0, loads pipeline.
    if (colk < rows) {
        float4 ar = {0.f, 0.f, 0.f, 0.f};
        const int hdb = wv * 16 + quad * 4;
        #pragma unroll 4
        for (int c = 0; c < 129; ++c) {
            float p = qrk_l[colk][c];
            float4 v4 = *(const float4*)(rpe_v + (size_t)c * HDD + hdb);
            ar.x = fmaf(p, v4.x, ar.x);
            ar.y = fmaf(p, v4.y, ar.y);
            ar.z = fmaf(p, v4.z, ar.z);
            ar.w = fmaf(p, v4.w, ar.w);
        }
        const float invS = stats_l[0][colk].w;
        float o0 = (2.f * (oaccA[0] + oaccB[0]) + ar.x) * invS;
        float o1 = (2.f * (oaccA[1] + oaccB[1]) + ar.y) * invS;
        float o2 = (2.f * (oaccA[2] + oaccB[2]) + ar.z) * invS;
        float o3 = (2.f * (oaccA[3] + oaccB[3]) + ar.w) * invS;
        size_t oo = ((size_t)(t0 + colk) * BB + b) * DD + h * HDD + hdb;
        ushort4 oh, ol;
        oh.x = f2bf(o0); ol.x = f2bf(o0 - bf2f(oh.x));
        oh.y = f2bf(o1); ol.y = f2bf(o1 - bf2f(oh.y));
        oh.z = f2bf(o2); ol.z = f2bf(o2 - bf2f(oh.z));
        oh.w = f2bf(o3); ol.w = f2bf(o3 - bf2f(oh.w));
        *(ushort4*)(ao_hi + oo) = oh;
        *(ushort4*)(ao_lo + oo) = ol;
    }
#undef LIVE
}

extern "C" void kernel_launch(void* const* d_in, const int* in_sizes, int n_in,
                              void* d_out, int out_size, void* d_ws, size_t ws_size,
                              hipStream_t stream) {
    const float*          x      = (const float*)d_in[0];
    const int*            lengths= (const int*)d_in[1];
    const float*          mems   = (const float*)d_in[2];
    const void*           amask  = (const void*)d_in[3];
    const int*            rpe    = (const int*)d_in[4];
    const float*          wq     = (const float*)d_in[6];
    const float*          bq     = (const float*)d_in[7];
    const float*          wkv    = (const float*)d_in[8];
    const float*          bkv    = (const float*)d_in[9];
    const float*          wo     = (const float*)d_in[10];
    const float*          bo     = (const float*)d_in[11];
    const float*          rpe_k  = (const float*)d_in[12];
    const float*          rpe_v  = (const float*)d_in[13];

    const size_t NE = (size_t)NROWS * DD;           // 3,268,608
    const size_t VTN = (size_t)NHEADS * HDD * VTS;  // 3,407,872

    char* p = (char*)d_ws;
    unsigned short* q_hi = (unsigned short*)p;  p += NE * 2;
    unsigned short* q_lo = (unsigned short*)p;  p += NE * 2;
    // union region: xs/ms (proj inputs, dead after proj) | vt (written after)
    char* uni = p;                              p += VTN * 4;   // vt is the larger
    unsigned short* xs_hi = (unsigned short*)uni;
    unsigned short* xs_lo = xs_hi + NE;
    unsigned short* ms_hi = xs_lo + NE;
    unsigned short* ms_lo = ms_hi + 48 * DD;
    unsigned short* vt_hi = (unsigned short*)uni;
    unsigned short* vt_lo = vt_hi + VTN;
    unsigned short* w_hi = (unsigned short*)p;  p += (size_t)2048 * DD * 2;
    unsigned short* w_lo = (unsigned short*)p;  p += (size_t)2048 * DD * 2;
    unsigned short* k_hi = (unsigned short*)p;  p += NE * 2;
    unsigned short* k_lo = (unsigned short*)p;  p += NE * 2;
    unsigned short* vr_hi = (unsigned short*)p; p += NE * 2;   // aliased by ao after transpose
    unsigned short* vr_lo = (unsigned short*)p; p += NE * 2;
    unsigned short* ao_hi = vr_hi;
    unsigned short* ao_lo = vr_lo;
    unsigned short* rk_hi = (unsigned short*)p; p += 144 * 64 * 2;
    unsigned short* rk_lo = (unsigned short*)p; p += 144 * 64 * 2;
    unsigned int*   pk2   = (unsigned int*)p;   p += (size_t)NTCH * 832 * 16;

    {
        const size_t sp_total = NE + (size_t)48 * DD + (size_t)2048 * DD;  // 4,341,760
        const int sp_blocks = (int)((sp_total + 1023) / 1024);             // 4,240
        prep_kernel<<<PK2_BLOCKS + RK_BLOCKS + sp_blocks, 256, 0, stream>>>(
            amask, rpe, pk2,
            rpe_k, rk_hi, rk_lo,
            x, mems, wq, wkv, wo,
            xs_hi, xs_lo, ms_hi, ms_lo, w_hi, w_lo);
    }
    mfma_proj<0><<<dim3(100, 8), 256, 0, stream>>>(
        xs_hi, xs_lo, nullptr, nullptr, w_hi, w_lo, bq,
        nullptr, q_hi, q_lo, nullptr, nullptr);
    mfma_proj<1><<<dim3(100, 16), 256, 0, stream>>>(
        xs_hi, xs_lo, ms_hi, ms_lo, w_hi + (size_t)512 * DD, w_lo + (size_t)512 * DD, bkv,
        nullptr, k_hi, k_lo, vr_hi, vr_lo);
    transpose_v_kernel<<<dim3(13, NHEADS), 256, 0, stream>>>(vr_hi, vr_lo, vt_hi, vt_lo);
    attn_kernel<<<3200, 256, 0, stream>>>(
        q_hi, q_lo, k_hi, k_lo, vt_hi, vt_lo, lengths, pk2, rk_hi, rk_lo, rpe_v, ao_hi, ao_lo);
    mfma_proj<2><<<dim3(100, 8), 256, 0, stream>>>(
        ao_hi, ao_lo, nullptr, nullptr, w_hi + (size_t)1536 * DD, w_lo + (size_t)1536 * DD, bo,
        (float*)d_out, nullptr, nullptr, nullptr, nullptr);
}

// Round 13
// 450.307 us; speedup vs baseline: 1.0831x; 1.0090x over previous
//
#include <hip/hip_runtime.h>
#include <hip/hip_bf16.h>
#include <math.h>

// Problem constants (fixed by the reference)
#define TT   799
#define BB   8
#define DD   512
#define HH   8
#define HDD  64
#define MMEM 6
#define RRCB 24
#define KLL  798
#define TQ   798            // query rows actually needed (row 798 unused)
#define NROWS (TQ * BB)     // 6384
#define NHEADS 64           // B*H
#define NEG_INF (-INFINITY)

#define TB   16             // t-rows per attention block
#define CH   64             // keys per MFMA chunk
#define NCH  13             // 13*64 = 832 >= 798
#define VTS  832            // v_t row stride in keys
#define NTCH 50             // t-chunks (50*16 = 800 >= TQ)
#define MINCH 7             // klen >= 430 always -> chunks 0..6 always live

static_assert(NROWS == 6384, "");

typedef __attribute__((ext_vector_type(8))) short short8;
typedef __attribute__((ext_vector_type(4))) float f32x4;

__device__ __forceinline__ unsigned short f2bf(float x) {
    union { float f; unsigned u; } c; c.f = x;
    unsigned r = c.u + 0x7FFFu + ((c.u >> 16) & 1u);   // RNE
    return (unsigned short)(r >> 16);
}
__device__ __forceinline__ float bf2f(unsigned short b) {
    union { unsigned u; float f; } c; c.u = ((unsigned)b) << 16; return c.f;
}

// Fused prep: transposed (mask,rpe)->rid pack pk2[t_chunk][key][row] |
// rpe_k hi/lo split | x/mems/W hi/lo split (float4-vectorized).
// Mask dtype (mode 0 = int32 0/1, 1 = float32, 2 = uint8) is detected
// IN-BLOCK from the first 4096 mask words (16KB, L2-hot, deterministic,
// block-uniform). v17 lesson: dtype MUST come from device data.
#define RK_BLOCKS 36
#define PK2_BLOCKS (NTCH * 13)   // 650: one block per (t_chunk, 64-key group)
__global__ __launch_bounds__(256)
void prep_kernel(const void* __restrict__ amask,
                 const int* __restrict__ rpe,
                 unsigned int* __restrict__ pk2,
                 const float* __restrict__ rpe_k,
                 unsigned short* __restrict__ rk_hi,
                 unsigned short* __restrict__ rk_lo,
                 const float* __restrict__ x,
                 const float* __restrict__ mems,
                 const float* __restrict__ wq,
                 const float* __restrict__ wkv,
                 const float* __restrict__ wo,
                 unsigned short* __restrict__ xs_hi, unsigned short* __restrict__ xs_lo,
                 unsigned short* __restrict__ ms_hi, unsigned short* __restrict__ ms_lo,
                 unsigned short* __restrict__ w_hi,  unsigned short* __restrict__ w_lo)
{
    const int bid = blockIdx.x;
    const int tid = threadIdx.x;
    if (bid < PK2_BLOCKS) {
        // in-block mask-dtype detection (identical result in every block)
        __shared__ int c0s, cHs;
        if (tid == 0) { c0s = 0; cHs = 0; }
        __syncthreads();
        {
            int c0 = 0, cH = 0;
            const unsigned* aw = (const unsigned*)amask;
            for (int i = tid; i < 4096; i += 256) {
                unsigned w = aw[i];
                if (w & 0x000000FFu) c0++;
                if (w & 0xFFFFFF00u) cH++;
            }
            atomicAdd(&c0s, c0); atomicAdd(&cHs, cH);
        }
        __syncthreads();
        const int mode = (cHs == 0) ? 0 : ((c0s == 0) ? 1 : 2);

        // transposed rid pack: byte (chunk, key, row) = rid or 255.
        const int chunk = bid / 13;
        const int kg = bid - chunk * 13;
        const int k64 = tid >> 2;          // 0..63
        const int word = tid & 3;          // covers rows word*4 .. word*4+3
        const int key = kg * 64 + k64;     // 0..831
        unsigned out = 0;
        #pragma unroll
        for (int r = 0; r < 4; ++r) {
            const int row = word * 4 + r;
            const int t = chunk * 16 + row;    // 0..799
            unsigned byte = 255u;
            if (key < KLL && t < TT) {
                size_t idx = (size_t)t * KLL + key;
                bool masked;
                if (mode == 0)      masked = (((const int*)amask)[idx] != 0);
                else if (mode == 1) masked = (((const float*)amask)[idx] != 0.f);
                else                masked = (((const unsigned char*)amask)[idx] != 0);
                byte = masked ? 255u : (unsigned)rpe[idx];
            }
            out |= byte << (8 * r);
        }
        pk2[((size_t)chunk * 832 + key) * 4 + word] = out;
    } else if (bid < PK2_BLOCKS + RK_BLOCKS) {
        int i = (bid - PK2_BLOCKS) * 256 + tid;
        if (i >= 144 * 64) return;
        int c = i >> 6;
        float v = (c < 129) ? rpe_k[i] : 0.f;
        unsigned short hi = f2bf(v);
        rk_hi[i] = hi;
        rk_lo[i] = f2bf(v - bf2f(hi));
    } else {
        // hi/lo split, 4 elements/thread (regions are all multiples of 4).
        const size_t NX = (size_t)NROWS * DD;
        const size_t NM = 48 * DD;
        const size_t NW = 2048 * DD;
        size_t i = ((size_t)(bid - PK2_BLOCKS - RK_BLOCKS) * 256 + tid) * 4;
        float4 v4; unsigned short *dh, *dl; size_t o;
        if (i < NX) { o = i; v4 = *(const float4*)(x + o); dh = xs_hi; dl = xs_lo; }
        else if (i < NX + NM) { o = i - NX; v4 = *(const float4*)(mems + o); dh = ms_hi; dl = ms_lo; }
        else if (i < NX + NM + NW) {
            o = i - NX - NM;
            size_t r = o >> 9;
            if (r < 512)       v4 = *(const float4*)(wq + o);
            else if (r < 1536) v4 = *(const float4*)(wkv + (o - (size_t)512 * DD));
            else               v4 = *(const float4*)(wo + (o - (size_t)1536 * DD));
            dh = w_hi; dl = w_lo;
        } else return;
        ushort4 h, lo;
        h.x = f2bf(v4.x); lo.x = f2bf(v4.x - bf2f(h.x));
        h.y = f2bf(v4.y); lo.y = f2bf(v4.y - bf2f(h.y));
        h.z = f2bf(v4.z); lo.z = f2bf(v4.z - bf2f(h.z));
        h.w = f2bf(v4.w); lo.w = f2bf(v4.w - bf2f(h.w));
        *(ushort4*)(dh + o) = h;
        *(ushort4*)(dl + o) = lo;
    }
}

// v row-major bf16 hi/lo [head][key][hd] -> v_t [head][hd][VTS] (keys 798..831 zero)
__global__ __launch_bounds__(256)
void transpose_v_kernel(const unsigned short* __restrict__ vr_hi,
                        const unsigned short* __restrict__ vr_lo,
                        unsigned short* __restrict__ vt_hi,
                        unsigned short* __restrict__ vt_lo)
{
    const int head = blockIdx.y;
    const int kb = blockIdx.x * 64;
    __shared__ unsigned short th[64][66];
    __shared__ unsigned short tl[64][66];
    const int tid = threadIdx.x;
    for (int i = tid; i < 64 * 64; i += 256) {
        int ky = i >> 6, hd = i & 63;
        int key = kb + ky;
        unsigned short hv = 0, lv = 0;
        if (key < KLL) {
            size_t o = ((size_t)head * KLL + key) * HDD + hd;
            hv = vr_hi[o]; lv = vr_lo[o];
        }
        th[ky][hd] = hv; tl[ky][hd] = lv;
    }
    __syncthreads();
    for (int i = tid; i < 64 * 64; i += 256) {
        int hd = i >> 6, ky = i & 63;
        size_t o = ((size_t)head * HDD + hd) * VTS + kb + ky;
        vt_hi[o] = th[ky][hd];
        vt_lo[o] = tl[ky][hd];
    }
}

// Fused Q/K/V projection, 64-row m-tiles (v16's proven geometry), LDS-staged
// W. Single 2400-block launch replaces the proj0(800)+proj1(1600) pair:
// removes one launch gap and fills proj0's tail with proj1 work. Per-element
// accumulation chain identical to the unfused version (same MFMA order).
// grid = dim3(100, 24): ny<8 -> q-path (W rows ny*64, bias bq, 0.125 scale);
// ny>=8 -> kv-path (W rows 512+(ny-8)*64, bias bkv, out k (nn<512) or vr).
__global__ __launch_bounds__(256, 4)
void proj_qkv64(const unsigned short* __restrict__ xs_hi,
                const unsigned short* __restrict__ xs_lo,
                const unsigned short* __restrict__ ms_hi,
                const unsigned short* __restrict__ ms_lo,
                const unsigned short* __restrict__ w_hi,
                const unsigned short* __restrict__ w_lo,
                const float* __restrict__ bq,
                const float* __restrict__ bkv,
                unsigned short* __restrict__ q_hi, unsigned short* __restrict__ q_lo,
                unsigned short* __restrict__ k_hi, unsigned short* __restrict__ k_lo,
                unsigned short* __restrict__ vr_hi, unsigned short* __restrict__ vr_lo)
{
    const int tid = threadIdx.x;
    const int wv = tid >> 6;
    const int quad = (tid >> 4) & 3;
    const int colk = tid & 15;
    const int m0 = blockIdx.x * 64;
    const int ny = blockIdx.y;
    const bool qpath = ny < 8;
    const int n0l = (qpath ? ny : ny - 8) * 64;      // local col base
    const int wr0 = qpath ? n0l : 512 + n0l;         // physical W row base

    __shared__ unsigned short wls_h[2][64][40];
    __shared__ unsigned short wls_l[2][64][40];

    const int sn = tid >> 2;
    const int sk = (tid & 3) * 8;
    const unsigned short* wsrc_h = w_hi + (size_t)(wr0 + sn) * DD + sk;
    const unsigned short* wsrc_l = w_lo + (size_t)(wr0 + sn) * DD + sk;

    const int am = min(m0 + wv * 16 + colk, NROWS - 1);
    const unsigned short *arh, *arl;
    if (qpath) {
        arh = xs_hi + (size_t)am * DD; arl = xs_lo + (size_t)am * DD;
    } else {
        if (am < 48) { arh = ms_hi + (size_t)am * DD; arl = ms_lo + (size_t)am * DD; }
        else         { arh = xs_hi + (size_t)(am - 48) * DD; arl = xs_lo + (size_t)(am - 48) * DD; }
    }

    f32x4 acc[4] = {{0,0,0,0},{0,0,0,0},{0,0,0,0},{0,0,0,0}};

    // stage k-step 0 into buf 0
    {
        short8 sh = *(const short8*)(wsrc_h);
        short8 sl = *(const short8*)(wsrc_l);
        *(short8*)&wls_h[0][sn][sk] = sh;
        *(short8*)&wls_l[0][sn][sk] = sl;
    }
    __syncthreads();

    #pragma unroll 2
    for (int ks = 0; ks < 16; ++ks) {
        const int buf = ks & 1;
        const int k0 = ks * 32;
        // prefetch next W tile to regs (no barrier dependency)
        short8 nh, nl;
        if (ks + 1 < 16) {
            nh = *(const short8*)(wsrc_h + k0 + 32);
            nl = *(const short8*)(wsrc_l + k0 + 32);
        }
        short8 ah = *(const short8*)(arh + k0 + quad * 8);
        short8 al = *(const short8*)(arl + k0 + quad * 8);
        #pragma unroll
        for (int nt = 0; nt < 4; ++nt) {
            short8 bh = *(const short8*)&wls_h[buf][nt * 16 + colk][quad * 8];
            short8 bl = *(const short8*)&wls_l[buf][nt * 16 + colk][quad * 8];
            acc[nt] = __builtin_amdgcn_mfma_f32_16x16x32_bf16(ah, bh, acc[nt], 0, 0, 0);
            acc[nt] = __builtin_amdgcn_mfma_f32_16x16x32_bf16(ah, bl, acc[nt], 0, 0, 0);
            acc[nt] = __builtin_amdgcn_mfma_f32_16x16x32_bf16(al, bh, acc[nt], 0, 0, 0);
        }
        if (ks + 1 < 16) {
            *(short8*)&wls_h[buf ^ 1][sn][sk] = nh;
            *(short8*)&wls_l[buf ^ 1][sn][sk] = nl;
        }
        __syncthreads();
    }

    #pragma unroll
    for (int nt = 0; nt < 4; ++nt) {
        const int nn = n0l + nt * 16 + colk;
        const float bv = qpath ? bq[nn] : bkv[nn];
        #pragma unroll
        for (int reg = 0; reg < 4; ++reg) {
            const int m = m0 + wv * 16 + quad * 4 + reg;
            if (m >= NROWS) continue;
            float v = acc[nt][reg] + bv;
            int row = m >> 3, bb = m & 7;
            if (qpath) {
                v *= 0.125f;
                int hh = nn >> 6, hd = nn & 63;
                size_t o = ((size_t)(bb * HH + hh) * TQ + row) * HDD + hd;
                unsigned short hi = f2bf(v);
                q_hi[o] = hi; q_lo[o] = f2bf(v - bf2f(hi));
            } else if (nn < DD) {
                int hh = nn >> 6, hd = nn & 63;
                size_t o = ((size_t)(bb * HH + hh) * KLL + row) * HDD + hd;
                unsigned short hi = f2bf(v);
                k_hi[o] = hi; k_lo[o] = f2bf(v - bf2f(hi));
            } else {
                int n2 = nn - DD;
                int hh = n2 >> 6, hd = n2 & 63;
                size_t o = ((size_t)(bb * HH + hh) * KLL + row) * HDD + hd;
                unsigned short hi = f2bf(v);
                vr_hi[o] = hi; vr_lo[o] = f2bf(v - bf2f(hi));
            }
        }
    }
}

// Output projection: A = ao, W = wo (base passed), out f32 + tanh tail rows.
// 64-row LDS-staged structure (v16).
__global__ __launch_bounds__(256, 4)
void proj_out(const unsigned short* __restrict__ a_hi,
              const unsigned short* __restrict__ a_lo,
              const unsigned short* __restrict__ w_hi,
              const unsigned short* __restrict__ w_lo,
              const float* __restrict__ bias,
              float* __restrict__ out_f)
{
    const int tid = threadIdx.x;
    const int wv = tid >> 6;
    const int quad = (tid >> 4) & 3;
    const int colk = tid & 15;
    const int m0 = blockIdx.x * 64;
    const int n0 = blockIdx.y * 64;

    __shared__ unsigned short wls_h[2][64][40];
    __shared__ unsigned short wls_l[2][64][40];

    const int sn = tid >> 2;
    const int sk = (tid & 3) * 8;
    const unsigned short* wsrc_h = w_hi + (size_t)(n0 + sn) * DD + sk;
    const unsigned short* wsrc_l = w_lo + (size_t)(n0 + sn) * DD + sk;

    const int am = min(m0 + wv * 16 + colk, NROWS - 1);
    const unsigned short* arh = a_hi + (size_t)am * DD;
    const unsigned short* arl = a_lo + (size_t)am * DD;

    f32x4 acc[4] = {{0,0,0,0},{0,0,0,0},{0,0,0,0},{0,0,0,0}};

    {
        short8 sh = *(const short8*)(wsrc_h);
        short8 sl = *(const short8*)(wsrc_l);
        *(short8*)&wls_h[0][sn][sk] = sh;
        *(short8*)&wls_l[0][sn][sk] = sl;
    }
    __syncthreads();

    #pragma unroll 2
    for (int ks = 0; ks < 16; ++ks) {
        const int buf = ks & 1;
        const int k0 = ks * 32;
        short8 nh, nl;
        if (ks + 1 < 16) {
            nh = *(const short8*)(wsrc_h + k0 + 32);
            nl = *(const short8*)(wsrc_l + k0 + 32);
        }
        short8 ah = *(const short8*)(arh + k0 + quad * 8);
        short8 al = *(const short8*)(arl + k0 + quad * 8);
        #pragma unroll
        for (int nt = 0; nt < 4; ++nt) {
            short8 bh = *(const short8*)&wls_h[buf][nt * 16 + colk][quad * 8];
            short8 bl = *(const short8*)&wls_l[buf][nt * 16 + colk][quad * 8];
            acc[nt] = __builtin_amdgcn_mfma_f32_16x16x32_bf16(ah, bh, acc[nt], 0, 0, 0);
            acc[nt] = __builtin_amdgcn_mfma_f32_16x16x32_bf16(ah, bl, acc[nt], 0, 0, 0);
            acc[nt] = __builtin_amdgcn_mfma_f32_16x16x32_bf16(al, bh, acc[nt], 0, 0, 0);
        }
        if (ks + 1 < 16) {
            *(short8*)&wls_h[buf ^ 1][sn][sk] = nh;
            *(short8*)&wls_l[buf ^ 1][sn][sk] = nl;
        }
        __syncthreads();
    }

    #pragma unroll
    for (int nt = 0; nt < 4; ++nt) {
        const int nn = n0 + nt * 16 + colk;
        const float bv = bias[nn];
        #pragma unroll
        for (int reg = 0; reg < 4; ++reg) {
            const int m = m0 + wv * 16 + quad * 4 + reg;
            if (m >= NROWS) continue;
            float v = acc[nt][reg] + bv;
            int row = m >> 3;
            if (row >= TQ - MMEM) v = tanhf(v);
            out_f[(size_t)m * DD + nn] = v;
        }
    }
}

// Attention: v14 numerics EXACT + s_setprio(1) around MFMA clusters (T5).
__global__ __launch_bounds__(256, 3)
void attn_kernel(const unsigned short* __restrict__ qh_g,
                 const unsigned short* __restrict__ ql_g,
                 const unsigned short* __restrict__ kh_g,
                 const unsigned short* __restrict__ kl_g,
                 const unsigned short* __restrict__ vt_hi,
                 const unsigned short* __restrict__ vt_lo,
                 const int* __restrict__ lengths,
                 const unsigned int* __restrict__ pk2,
                 const unsigned short* __restrict__ rk_hi,
                 const unsigned short* __restrict__ rk_lo,
                 const float* __restrict__ rpe_v,
                 unsigned short* __restrict__ ao_hi,
                 unsigned short* __restrict__ ao_lo)
{
    // XCD-aware decode: xcd = id&7 fixed per head; t-chunks consecutive.
    const int id = blockIdx.x;
    const int xcd = id & 7;
    const int grp = id >> 3;             // 0..399
    const int t_chunk = grp % NTCH;
    const int n = (grp / NTCH) * 8 + xcd; // head index 0..63
    const int t0 = t_chunk * TB;
    const int rows = min(TB, TQ - t0);
    const int b = n >> 3;
    const int h = n & 7;
    const int tid = threadIdx.x;
    const int wv = tid >> 6;
    const int quad = (tid >> 4) & 3;
    const int colk = tid & 15;
    const int myk = wv * 16 + colk;

    __shared__ float qrk_l[TB][132];                 // qrk, then pr buckets (8448 B)
    __shared__ unsigned short p_hi[2][TB][72];       // 4608 B
    __shared__ unsigned short p_lo[2][TB][72];       // 4608 B
    __shared__ float4 stats_l[4][TB];                // 1024 B

    const int klen = lengths[b] + MMEM + RRCB;
    const int nch_live = (klen + CH - 1) / CH;       // block-uniform, 7..13
    const unsigned* pkg = pk2 + (size_t)t_chunk * 832 * 4;  // u32 units

#define LIVE(c) ((c) < MINCH || (c) < nch_live)

    // A fragments (Q), direct global, held all kernel. A row = query row colk.
    const int qrow = t0 + min(colk, rows - 1);
    const size_t qo = ((size_t)n * TQ + qrow) * HDD;
    short8 ah0 = *(const short8*)(qh_g + qo + quad * 8);
    short8 ah1 = *(const short8*)(qh_g + qo + 32 + quad * 8);
    short8 al0 = *(const short8*)(ql_g + qo + quad * 8);
    short8 al1 = *(const short8*)(ql_g + qo + 32 + quad * 8);

    // qrk via MFMA: wave wv does rpe_k row-tiles wv, wv+4, wv+8
    for (int t = wv; t < 9; t += 4) {
        const size_t rb = (size_t)(t * 16 + colk) * 64;
        short8 bh0 = *(const short8*)(rk_hi + rb + quad * 8);
        short8 bh1 = *(const short8*)(rk_hi + rb + 32 + quad * 8);
        short8 bl0 = *(const short8*)(rk_lo + rb + quad * 8);
        short8 bl1 = *(const short8*)(rk_lo + rb + 32 + quad * 8);
        f32x4 c4 = {0.f, 0.f, 0.f, 0.f};
        __builtin_amdgcn_s_setprio(1);
        c4 = __builtin_amdgcn_mfma_f32_16x16x32_bf16(ah0, bh0, c4, 0, 0, 0);
        c4 = __builtin_amdgcn_mfma_f32_16x16x32_bf16(ah1, bh1, c4, 0, 0, 0);
        c4 = __builtin_amdgcn_mfma_f32_16x16x32_bf16(ah0, bl0, c4, 0, 0, 0);
        c4 = __builtin_amdgcn_mfma_f32_16x16x32_bf16(ah1, bl1, c4, 0, 0, 0);
        c4 = __builtin_amdgcn_mfma_f32_16x16x32_bf16(al0, bh0, c4, 0, 0, 0);
        c4 = __builtin_amdgcn_mfma_f32_16x16x32_bf16(al1, bh1, c4, 0, 0, 0);
        __builtin_amdgcn_s_setprio(0);
        int c = t * 16 + colk;
        if (c <= 128) {
            #pragma unroll
            for (int reg = 0; reg < 4; ++reg) qrk_l[quad * 4 + reg][c] = c4[reg];
        }
    }
    __syncthreads();

    // ---- pass A: QK^T MFMA, record scores + max (live chunks only) ----
    float s_reg[NCH][4];
    float mx[4] = {-1e30f, -1e30f, -1e30f, -1e30f};

    #pragma unroll
    for (int cc = 0; cc < NCH; ++cc) {
        if (LIVE(cc)) {
            const int key = cc * CH + myk;
            const int krow = min(key, KLL - 1);
            const size_t ko = ((size_t)n * KLL + krow) * HDD;
            const unsigned r4 = pkg[key * 4 + quad];   // early: hides under MFMAs
            short8 bh0 = *(const short8*)(kh_g + ko + quad * 8);
            short8 bh1 = *(const short8*)(kh_g + ko + 32 + quad * 8);
            short8 bl0 = *(const short8*)(kl_g + ko + quad * 8);
            short8 bl1 = *(const short8*)(kl_g + ko + 32 + quad * 8);
            f32x4 c4a = {0.f, 0.f, 0.f, 0.f};
            f32x4 c4b = {0.f, 0.f, 0.f, 0.f};
            __builtin_amdgcn_s_setprio(1);
            c4a = __builtin_amdgcn_mfma_f32_16x16x32_bf16(ah0, bh0, c4a, 0, 0, 0);
            c4b = __builtin_amdgcn_mfma_f32_16x16x32_bf16(ah1, bh1, c4b, 0, 0, 0);
            c4a = __builtin_amdgcn_mfma_f32_16x16x32_bf16(ah0, bl0, c4a, 0, 0, 0);
            c4b = __builtin_amdgcn_mfma_f32_16x16x32_bf16(ah1, bl1, c4b, 0, 0, 0);
            c4a = __builtin_amdgcn_mfma_f32_16x16x32_bf16(al0, bh0, c4a, 0, 0, 0);
            c4b = __builtin_amdgcn_mfma_f32_16x16x32_bf16(al1, bh1, c4b, 0, 0, 0);
            __builtin_amdgcn_s_setprio(0);

            const bool vkey = (key < klen);
            #pragma unroll
            for (int reg = 0; reg < 4; ++reg) {
                const int row = quad * 4 + reg;
                const unsigned rid = (r4 >> (8 * reg)) & 255u;
                const float qv = qrk_l[row][min(rid, 128u)];   // clamped gather
                float s = (c4a[reg] + c4b[reg]) + qv;
                const bool ok = vkey && (row < rows) && (rid != 255u);
                s = ok ? s : -1e30f;
                mx[reg] = fmaxf(mx[reg], s);
                s_reg[cc][reg] = s;
            }
        } else {
            #pragma unroll
            for (int reg = 0; reg < 4; ++reg) s_reg[cc][reg] = -1e30f;
        }
    }

    // max merge: shfl16 then cross-wave
    #pragma unroll
    for (int reg = 0; reg < 4; ++reg)
        #pragma unroll
        for (int d = 1; d < 16; d <<= 1) mx[reg] = fmaxf(mx[reg], __shfl_xor(mx[reg], d, 16));
    if (colk == 0) {
        #pragma unroll
        for (int reg = 0; reg < 4; ++reg)
            stats_l[wv][quad * 4 + reg] = make_float4(mx[reg], 0.f, 0.f, 0.f);
    }
    __syncthreads();
    if (tid < TB) {
        float M = fmaxf(fmaxf(stats_l[0][tid].x, stats_l[1][tid].x),
                        fmaxf(stats_l[2][tid].x, stats_l[3][tid].x));
        stats_l[0][tid].x = M;
    }
    __syncthreads();

    // e-sweep (branchless): e = exp(s - M) (underflows to 0 for dead),
    // overwrite s_reg; accumulate l, l2, count (count via select).
    float Mr[4], l[4] = {0,0,0,0}, l2[4] = {0,0,0,0}, cn[4] = {0,0,0,0};
    #pragma unroll
    for (int reg = 0; reg < 4; ++reg) Mr[reg] = stats_l[0][quad * 4 + reg].x;
    #pragma unroll
    for (int cc = 0; cc < NCH; ++cc) {
        if (LIVE(cc)) {
            #pragma unroll
            for (int reg = 0; reg < 4; ++reg) {
                float s = s_reg[cc][reg];
                float e = expf(s - Mr[reg]);
                cn[reg] += (s > -1e29f) ? 1.f : 0.f;
                l[reg] += e;
                l2[reg] = fmaf(e, e, l2[reg]);
                s_reg[cc][reg] = e;
            }
        }
    }
    #pragma unroll
    for (int reg = 0; reg < 4; ++reg)
        #pragma unroll
        for (int d = 1; d < 16; d <<= 1) {
            l[reg]  += __shfl_xor(l[reg], d, 16);
            l2[reg] += __shfl_xor(l2[reg], d, 16);
            cn[reg] += __shfl_xor(cn[reg], d, 16);
        }
    if (colk == 0) {
        #pragma unroll
        for (int reg = 0; reg < 4; ++reg)
            stats_l[wv][quad * 4 + reg] = make_float4(Mr[reg], l[reg], l2[reg], cn[reg]);
    }
    __syncthreads();
    if (tid < TB) {
        float L = 0.f, L2 = 0.f, C = 0.f;
        #pragma unroll
        for (int w = 0; w < 4; ++w) {
            float4 s4 = stats_l[w][tid];
            L += s4.y; L2 += s4.z; C += s4.w;
        }
        float inv = (L > 0.f) ? 1.f / L : 0.f;
        float mean = 1.f / (C + 1e-8f);
        float sump2 = L2 * inv * inv;
        float var = (sump2 - 2.f * mean + C * mean * mean) / (C - 1.f + 1e-8f);
        var = fmaxf(var, 0.f);
        float thr = mean - 0.5f * sqrtf(var);
        stats_l[0][tid] = make_float4(stats_l[0][tid].x, inv, thr, 0.f);
    }
    // zero pr (qrk_l reuse; scores are stored, qrk dead after pass A)
    for (int i = tid; i < TB * 132; i += 256) ((float*)qrk_l)[i] = 0.f;
    __syncthreads();

    // ---- pass B: p = e*inv, threshold, buckets, PV via MFMA (live only) ----
    float inv_r[4], thr_r[4];
    #pragma unroll
    for (int reg = 0; reg < 4; ++reg) {
        float4 s4 = stats_l[0][quad * 4 + reg];
        inv_r[reg] = s4.y; thr_r[reg] = s4.z;
    }
    float sig[4] = {0.f, 0.f, 0.f, 0.f};
    f32x4 oaccA = {0.f, 0.f, 0.f, 0.f};
    f32x4 oaccB = {0.f, 0.f, 0.f, 0.f};

    auto computeP = [&](int cc, int buf, unsigned r4) {
        #pragma unroll
        for (int reg = 0; reg < 4; ++reg) {
            const int row = quad * 4 + reg;
            float p = s_reg[cc][reg] * inv_r[reg];
            if (p < thr_r[reg]) p = 0.f;
            sig[reg] += p;
            if (p > 0.f) {
                unsigned rid = (r4 >> (8 * reg)) & 255u;
                atomicAdd(&qrk_l[row][rid], p);
            }
            unsigned short ph = f2bf(p);
            p_hi[buf][row][myk] = ph;
            p_lo[buf][row][myk] = f2bf(p - bf2f(ph));
        }
    };

    // V fragment registers (current + prefetch handled per iteration)
    short8 vh0, vh1, vl0, vl1;
    {
        const size_t vbase = ((size_t)n * HDD + wv * 16 + colk) * VTS;
        vh0 = *(const short8*)(vt_hi + vbase + quad * 8);
        vh1 = *(const short8*)(vt_hi + vbase + 32 + quad * 8);
        vl0 = *(const short8*)(vt_lo + vbase + quad * 8);
        vl1 = *(const short8*)(vt_lo + vbase + 32 + quad * 8);
    }
    computeP(0, 0, pkg[myk * 4 + quad]);
    __syncthreads();
    #pragma unroll
    for (int cc = 0; cc < NCH; ++cc) {
        if (LIVE(cc)) {
            const bool nlive = (cc + 1 < NCH) && LIVE(cc + 1);
            // prefetch next chunk's V frags + pk word (global: no barrier dep)
            short8 nvh0, nvh1, nvl0, nvl1; unsigned nr4 = 0;
            if (nlive) {
                const size_t vbase = ((size_t)n * HDD + wv * 16 + colk) * VTS
                                   + (cc + 1) * CH;
                nvh0 = *(const short8*)(vt_hi + vbase + quad * 8);
                nvh1 = *(const short8*)(vt_hi + vbase + 32 + quad * 8);
                nvl0 = *(const short8*)(vt_lo + vbase + quad * 8);
                nvl1 = *(const short8*)(vt_lo + vbase + 32 + quad * 8);
                nr4 = pkg[((cc + 1) * CH + myk) * 4 + quad];
            }
            const int buf = cc & 1;
            short8 ph0 = *(const short8*)&p_hi[buf][colk][quad * 8];
            short8 ph1 = *(const short8*)&p_hi[buf][colk][32 + quad * 8];
            short8 pl0 = *(const short8*)&p_lo[buf][colk][quad * 8];
            short8 pl1 = *(const short8*)&p_lo[buf][colk][32 + quad * 8];
            __builtin_amdgcn_s_setprio(1);
            oaccA = __builtin_amdgcn_mfma_f32_16x16x32_bf16(vh0, ph0, oaccA, 0, 0, 0);
            oaccB = __builtin_amdgcn_mfma_f32_16x16x32_bf16(vh1, ph1, oaccB, 0, 0, 0);
            oaccA = __builtin_amdgcn_mfma_f32_16x16x32_bf16(vh0, pl0, oaccA, 0, 0, 0);
            oaccB = __builtin_amdgcn_mfma_f32_16x16x32_bf16(vh1, pl1, oaccB, 0, 0, 0);
            oaccA = __builtin_amdgcn_mfma_f32_16x16x32_bf16(vl0, ph0, oaccA, 0, 0, 0);
            oaccB = __builtin_amdgcn_mfma_f32_16x16x32_bf16(vl1, ph1, oaccB, 0, 0, 0);
            __builtin_amdgcn_s_setprio(0);
            if (nlive) computeP(cc + 1, (cc + 1) & 1, nr4);
            __syncthreads();
            if (nlive) { vh0 = nvh0; vh1 = nvh1; vl0 = nvl0; vl1 = nvl1; }
        }
    }

    // survivor-sum merge
    #pragma unroll
    for (int reg = 0; reg < 4; ++reg)
        #pragma unroll
        for (int d = 1; d < 16; d <<= 1) sig[reg] += __shfl_xor(sig[reg], d, 16);
    if (colk == 0) {
        #pragma unroll
        for (int reg = 0; reg < 4; ++reg)
            stats_l[wv][quad * 4 + reg].w = sig[reg];
    }
    __syncthreads();
    if (tid < TB) {
        float S = stats_l[0][tid].w + stats_l[1][tid].w + stats_l[2][tid].w + stats_l[3][tid].w;
        stats_l[0][tid].w = (S > 0.f) ? 1.f / S : 0.f;
    }
    __syncthreads();

    // output: lane owns O[row=colk][hd = wv*16 + quad*4 .. +3], bf16 hi/lo.
    // Branchless bucket dot: p == 0 contributes exactly 0, loads pipeline.
    if (colk < rows) {
        float4 ar = {0.f, 0.f, 0.f, 0.f};
        const int hdb = wv * 16 + quad * 4;
        #pragma unroll 4
        for (int c = 0; c < 129; ++c) {
            float p = qrk_l[colk][c];
            float4 v4 = *(const float4*)(rpe_v + (size_t)c * HDD + hdb);
            ar.x = fmaf(p, v4.x, ar.x);
            ar.y = fmaf(p, v4.y, ar.y);
            ar.z = fmaf(p, v4.z, ar.z);
            ar.w = fmaf(p, v4.w, ar.w);
        }
        const float invS = stats_l[0][colk].w;
        float o0 = (2.f * (oaccA[0] + oaccB[0]) + ar.x) * invS;
        float o1 = (2.f * (oaccA[1] + oaccB[1]) + ar.y) * invS;
        float o2 = (2.f * (oaccA[2] + oaccB[2]) + ar.z) * invS;
        float o3 = (2.f * (oaccA[3] + oaccB[3]) + ar.w) * invS;
        size_t oo = ((size_t)(t0 + colk) * BB + b) * DD + h * HDD + hdb;
        ushort4 oh, ol;
        oh.x = f2bf(o0); ol.x = f2bf(o0 - bf2f(oh.x));
        oh.y = f2bf(o1); ol.y = f2bf(o1 - bf2f(oh.y));
        oh.z = f2bf(o2); ol.z = f2bf(o2 - bf2f(oh.z));
        oh.w = f2bf(o3); ol.w = f2bf(o3 - bf2f(oh.w));
        *(ushort4*)(ao_hi + oo) = oh;
        *(ushort4*)(ao_lo + oo) = ol;
    }
#undef LIVE
}

extern "C" void kernel_launch(void* const* d_in, const int* in_sizes, int n_in,
                              void* d_out, int out_size, void* d_ws, size_t ws_size,
                              hipStream_t stream) {
    const float*          x      = (const float*)d_in[0];
    const int*            lengths= (const int*)d_in[1];
    const float*          mems   = (const float*)d_in[2];
    const void*           amask  = (const void*)d_in[3];
    const int*            rpe    = (const int*)d_in[4];
    const float*          wq     = (const float*)d_in[6];
    const float*          bq     = (const float*)d_in[7];
    const float*          wkv    = (const float*)d_in[8];
    const float*          bkv    = (const float*)d_in[9];
    const float*          wo     = (const float*)d_in[10];
    const float*          bo     = (const float*)d_in[11];
    const float*          rpe_k  = (const float*)d_in[12];
    const float*          rpe_v  = (const float*)d_in[13];

    const size_t NE = (size_t)NROWS * DD;           // 3,268,608
    const size_t VTN = (size_t)NHEADS * HDD * VTS;  // 3,407,872

    char* p = (char*)d_ws;
    unsigned short* q_hi = (unsigned short*)p;  p += NE * 2;
    unsigned short* q_lo = (unsigned short*)p;  p += NE * 2;
    // union region: xs/ms (proj inputs, dead after proj) | vt (written after)
    char* uni = p;                              p += VTN * 4;   // vt is the larger
    unsigned short* xs_hi = (unsigned short*)uni;
    unsigned short* xs_lo = xs_hi + NE;
    unsigned short* ms_hi = xs_lo + NE;
    unsigned short* ms_lo = ms_hi + 48 * DD;
    unsigned short* vt_hi = (unsigned short*)uni;
    unsigned short* vt_lo = vt_hi + VTN;
    unsigned short* w_hi = (unsigned short*)p;  p += (size_t)2048 * DD * 2;
    unsigned short* w_lo = (unsigned short*)p;  p += (size_t)2048 * DD * 2;
    unsigned short* k_hi = (unsigned short*)p;  p += NE * 2;
    unsigned short* k_lo = (unsigned short*)p;  p += NE * 2;
    unsigned short* vr_hi = (unsigned short*)p; p += NE * 2;   // aliased by ao after transpose
    unsigned short* vr_lo = (unsigned short*)p; p += NE * 2;
    unsigned short* ao_hi = vr_hi;
    unsigned short* ao_lo = vr_lo;
    unsigned short* rk_hi = (unsigned short*)p; p += 144 * 64 * 2;
    unsigned short* rk_lo = (unsigned short*)p; p += 144 * 64 * 2;
    unsigned int*   pk2   = (unsigned int*)p;   p += (size_t)NTCH * 832 * 16;

    {
        const size_t sp_total = NE + (size_t)48 * DD + (size_t)2048 * DD;  // 4,341,760
        const int sp_blocks = (int)((sp_total + 1023) / 1024);             // 4,240
        prep_kernel<<<PK2_BLOCKS + RK_BLOCKS + sp_blocks, 256, 0, stream>>>(
            amask, rpe, pk2,
            rpe_k, rk_hi, rk_lo,
            x, mems, wq, wkv, wo,
            xs_hi, xs_lo, ms_hi, ms_lo, w_hi, w_lo);
    }
    proj_qkv64<<<dim3(100, 24), 256, 0, stream>>>(
        xs_hi, xs_lo, ms_hi, ms_lo, w_hi, w_lo, bq, bkv,
        q_hi, q_lo, k_hi, k_lo, vr_hi, vr_lo);
    transpose_v_kernel<<<dim3(13, NHEADS), 256, 0, stream>>>(vr_hi, vr_lo, vt_hi, vt_lo);
    attn_kernel<<<3200, 256, 0, stream>>>(
        q_hi, q_lo, k_hi, k_lo, vt_hi, vt_lo, lengths, pk2, rk_hi, rk_lo, rpe_v, ao_hi, ao_lo);
    proj_out<<<dim3(100, 8), 256, 0, stream>>>(
        ao_hi, ao_lo, w_hi + (size_t)1536 * DD, w_lo + (size_t)1536 * DD, bo,
        (float*)d_out);
}

// Round 15
// 449.079 us; speedup vs baseline: 1.0861x; 1.0027x over previous
//
#include <hip/hip_runtime.h>
#include <hip/hip_bf16.h>
#include <math.h>

// Problem constants (fixed by the reference)
#define TT   799
#define BB   8
#define DD   512
#define HH   8
#define HDD  64
#define MMEM 6
#define RRCB 24
#define KLL  798
#define TQ   798            // query rows actually needed (row 798 unused)
#define NROWS (TQ * BB)     // 6384
#define NHEADS 64           // B*H
#define NEG_INF (-INFINITY)

#define TB   16             // t-rows per attention block
#define CH   64             // keys per MFMA chunk
#define NCH  13             // 13*64 = 832 >= 798
#define VTS  832            // v_t row stride in keys
#define NTCH 50             // t-chunks (50*16 = 800 >= TQ)
#define MINCH 7             // klen >= 430 always -> chunks 0..6 always live

static_assert(NROWS == 6384, "");

typedef __attribute__((ext_vector_type(8))) short short8;
typedef __attribute__((ext_vector_type(4))) float f32x4;

__device__ __forceinline__ unsigned short f2bf(float x) {
    union { float f; unsigned u; } c; c.f = x;
    unsigned r = c.u + 0x7FFFu + ((c.u >> 16) & 1u);   // RNE
    return (unsigned short)(r >> 16);
}
__device__ __forceinline__ float bf2f(unsigned short b) {
    union { unsigned u; float f; } c; c.u = ((unsigned)b) << 16; return c.f;
}

// Fused prep: transposed (mask,rpe)->rid pack pk2[t_chunk][key][row] |
// rpe_k hi/lo split | x/mems/W hi/lo split (float4-vectorized).
// Mask dtype (mode 0 = int32 0/1, 1 = float32, 2 = uint8) is detected
// IN-BLOCK from the first 4096 mask words (16KB, L2-hot, deterministic,
// block-uniform). v17 lesson: dtype MUST come from device data.
#define RK_BLOCKS 36
#define PK2_BLOCKS (NTCH * 13)   // 650: one block per (t_chunk, 64-key group)
__global__ __launch_bounds__(256)
void prep_kernel(const void* __restrict__ amask,
                 const int* __restrict__ rpe,
                 unsigned int* __restrict__ pk2,
                 const float* __restrict__ rpe_k,
                 unsigned short* __restrict__ rk_hi,
                 unsigned short* __restrict__ rk_lo,
                 const float* __restrict__ x,
                 const float* __restrict__ mems,
                 const float* __restrict__ wq,
                 const float* __restrict__ wkv,
                 const float* __restrict__ wo,
                 unsigned short* __restrict__ xs_hi, unsigned short* __restrict__ xs_lo,
                 unsigned short* __restrict__ ms_hi, unsigned short* __restrict__ ms_lo,
                 unsigned short* __restrict__ w_hi,  unsigned short* __restrict__ w_lo)
{
    const int bid = blockIdx.x;
    const int tid = threadIdx.x;
    if (bid < PK2_BLOCKS) {
        // in-block mask-dtype detection (identical result in every block)
        __shared__ int c0s, cHs;
        if (tid == 0) { c0s = 0; cHs = 0; }
        __syncthreads();
        {
            int c0 = 0, cH = 0;
            const unsigned* aw = (const unsigned*)amask;
            for (int i = tid; i < 4096; i += 256) {
                unsigned w = aw[i];
                if (w & 0x000000FFu) c0++;
                if (w & 0xFFFFFF00u) cH++;
            }
            atomicAdd(&c0s, c0); atomicAdd(&cHs, cH);
        }
        __syncthreads();
        const int mode = (cHs == 0) ? 0 : ((c0s == 0) ? 1 : 2);

        // transposed rid pack: byte (chunk, key, row) = rid or 255.
        const int chunk = bid / 13;
        const int kg = bid - chunk * 13;
        const int k64 = tid >> 2;          // 0..63
        const int word = tid & 3;          // covers rows word*4 .. word*4+3
        const int key = kg * 64 + k64;     // 0..831
        unsigned out = 0;
        #pragma unroll
        for (int r = 0; r < 4; ++r) {
            const int row = word * 4 + r;
            const int t = chunk * 16 + row;    // 0..799
            unsigned byte = 255u;
            if (key < KLL && t < TT) {
                size_t idx = (size_t)t * KLL + key;
                bool masked;
                if (mode == 0)      masked = (((const int*)amask)[idx] != 0);
                else if (mode == 1) masked = (((const float*)amask)[idx] != 0.f);
                else                masked = (((const unsigned char*)amask)[idx] != 0);
                byte = masked ? 255u : (unsigned)rpe[idx];
            }
            out |= byte << (8 * r);
        }
        pk2[((size_t)chunk * 832 + key) * 4 + word] = out;
    } else if (bid < PK2_BLOCKS + RK_BLOCKS) {
        int i = (bid - PK2_BLOCKS) * 256 + tid;
        if (i >= 144 * 64) return;
        int c = i >> 6;
        float v = (c < 129) ? rpe_k[i] : 0.f;
        unsigned short hi = f2bf(v);
        rk_hi[i] = hi;
        rk_lo[i] = f2bf(v - bf2f(hi));
    } else {
        // hi/lo split, 4 elements/thread (regions are all multiples of 4).
        const size_t NX = (size_t)NROWS * DD;
        const size_t NM = 48 * DD;
        const size_t NW = 2048 * DD;
        size_t i = ((size_t)(bid - PK2_BLOCKS - RK_BLOCKS) * 256 + tid) * 4;
        float4 v4; unsigned short *dh, *dl; size_t o;
        if (i < NX) { o = i; v4 = *(const float4*)(x + o); dh = xs_hi; dl = xs_lo; }
        else if (i < NX + NM) { o = i - NX; v4 = *(const float4*)(mems + o); dh = ms_hi; dl = ms_lo; }
        else if (i < NX + NM + NW) {
            o = i - NX - NM;
            size_t r = o >> 9;
            if (r < 512)       v4 = *(const float4*)(wq + o);
            else if (r < 1536) v4 = *(const float4*)(wkv + (o - (size_t)512 * DD));
            else               v4 = *(const float4*)(wo + (o - (size_t)1536 * DD));
            dh = w_hi; dl = w_lo;
        } else return;
        ushort4 h, lo;
        h.x = f2bf(v4.x); lo.x = f2bf(v4.x - bf2f(h.x));
        h.y = f2bf(v4.y); lo.y = f2bf(v4.y - bf2f(h.y));
        h.z = f2bf(v4.z); lo.z = f2bf(v4.z - bf2f(h.z));
        h.w = f2bf(v4.w); lo.w = f2bf(v4.w - bf2f(h.w));
        *(ushort4*)(dh + o) = h;
        *(ushort4*)(dl + o) = lo;
    }
}

// v row-major bf16 hi/lo [head][key][hd] -> v_t [head][hd][VTS] (keys 798..831 zero)
__global__ __launch_bounds__(256)
void transpose_v_kernel(const unsigned short* __restrict__ vr_hi,
                        const unsigned short* __restrict__ vr_lo,
                        unsigned short* __restrict__ vt_hi,
                        unsigned short* __restrict__ vt_lo)
{
    const int head = blockIdx.y;
    const int kb = blockIdx.x * 64;
    __shared__ unsigned short th[64][66];
    __shared__ unsigned short tl[64][66];
    const int tid = threadIdx.x;
    for (int i = tid; i < 64 * 64; i += 256) {
        int ky = i >> 6, hd = i & 63;
        int key = kb + ky;
        unsigned short hv = 0, lv = 0;
        if (key < KLL) {
            size_t o = ((size_t)head * KLL + key) * HDD + hd;
            hv = vr_hi[o]; lv = vr_lo[o];
        }
        th[ky][hd] = hv; tl[ky][hd] = lv;
    }
    __syncthreads();
    for (int i = tid; i < 64 * 64; i += 256) {
        int hd = i >> 6, ky = i & 63;
        size_t o = ((size_t)head * HDD + hd) * VTS + kb + ky;
        vt_hi[o] = th[ky][hd];
        vt_lo[o] = tl[ky][hd];
    }
}

// Fused Q/K/V projection, 64-row m-tiles (v16's proven geometry), LDS-staged
// W. Single 2400-block launch replaces the proj0(800)+proj1(1600) pair:
// removes one launch gap and fills proj0's tail with proj1 work. Per-element
// accumulation chain identical to the unfused version (same MFMA order).
// grid = dim3(100, 24): ny<8 -> q-path (W rows ny*64, bias bq, 0.125 scale);
// ny>=8 -> kv-path (W rows 512+(ny-8)*64, bias bkv, out k (nn<512) or vr).
__global__ __launch_bounds__(256, 4)
void proj_qkv64(const unsigned short* __restrict__ xs_hi,
                const unsigned short* __restrict__ xs_lo,
                const unsigned short* __restrict__ ms_hi,
                const unsigned short* __restrict__ ms_lo,
                const unsigned short* __restrict__ w_hi,
                const unsigned short* __restrict__ w_lo,
                const float* __restrict__ bq,
                const float* __restrict__ bkv,
                unsigned short* __restrict__ q_hi, unsigned short* __restrict__ q_lo,
                unsigned short* __restrict__ k_hi, unsigned short* __restrict__ k_lo,
                unsigned short* __restrict__ vr_hi, unsigned short* __restrict__ vr_lo)
{
    const int tid = threadIdx.x;
    const int wv = tid >> 6;
    const int quad = (tid >> 4) & 3;
    const int colk = tid & 15;
    const int m0 = blockIdx.x * 64;
    const int ny = blockIdx.y;
    const bool qpath = ny < 8;
    const int n0l = (qpath ? ny : ny - 8) * 64;      // local col base
    const int wr0 = qpath ? n0l : 512 + n0l;         // physical W row base

    __shared__ unsigned short wls_h[2][64][40];
    __shared__ unsigned short wls_l[2][64][40];

    const int sn = tid >> 2;
    const int sk = (tid & 3) * 8;
    const unsigned short* wsrc_h = w_hi + (size_t)(wr0 + sn) * DD + sk;
    const unsigned short* wsrc_l = w_lo + (size_t)(wr0 + sn) * DD + sk;

    const int am = min(m0 + wv * 16 + colk, NROWS - 1);
    const unsigned short *arh, *arl;
    if (qpath) {
        arh = xs_hi + (size_t)am * DD; arl = xs_lo + (size_t)am * DD;
    } else {
        if (am < 48) { arh = ms_hi + (size_t)am * DD; arl = ms_lo + (size_t)am * DD; }
        else         { arh = xs_hi + (size_t)(am - 48) * DD; arl = xs_lo + (size_t)(am - 48) * DD; }
    }

    f32x4 acc[4] = {{0,0,0,0},{0,0,0,0},{0,0,0,0},{0,0,0,0}};

    // stage k-step 0 into buf 0
    {
        short8 sh = *(const short8*)(wsrc_h);
        short8 sl = *(const short8*)(wsrc_l);
        *(short8*)&wls_h[0][sn][sk] = sh;
        *(short8*)&wls_l[0][sn][sk] = sl;
    }
    __syncthreads();

    #pragma unroll 2
    for (int ks = 0; ks < 16; ++ks) {
        const int buf = ks & 1;
        const int k0 = ks * 32;
        // prefetch next W tile to regs (no barrier dependency)
        short8 nh, nl;
        if (ks + 1 < 16) {
            nh = *(const short8*)(wsrc_h + k0 + 32);
            nl = *(const short8*)(wsrc_l + k0 + 32);
        }
        short8 ah = *(const short8*)(arh + k0 + quad * 8);
        short8 al = *(const short8*)(arl + k0 + quad * 8);
        #pragma unroll
        for (int nt = 0; nt < 4; ++nt) {
            short8 bh = *(const short8*)&wls_h[buf][nt * 16 + colk][quad * 8];
            short8 bl = *(const short8*)&wls_l[buf][nt * 16 + colk][quad * 8];
            acc[nt] = __builtin_amdgcn_mfma_f32_16x16x32_bf16(ah, bh, acc[nt], 0, 0, 0);
            acc[nt] = __builtin_amdgcn_mfma_f32_16x16x32_bf16(ah, bl, acc[nt], 0, 0, 0);
            acc[nt] = __builtin_amdgcn_mfma_f32_16x16x32_bf16(al, bh, acc[nt], 0, 0, 0);
        }
        if (ks + 1 < 16) {
            *(short8*)&wls_h[buf ^ 1][sn][sk] = nh;
            *(short8*)&wls_l[buf ^ 1][sn][sk] = nl;
        }
        __syncthreads();
    }

    #pragma unroll
    for (int nt = 0; nt < 4; ++nt) {
        const int nn = n0l + nt * 16 + colk;
        const float bv = qpath ? bq[nn] : bkv[nn];
        #pragma unroll
        for (int reg = 0; reg < 4; ++reg) {
            const int m = m0 + wv * 16 + quad * 4 + reg;
            if (m >= NROWS) continue;
            float v = acc[nt][reg] + bv;
            int row = m >> 3, bb = m & 7;
            if (qpath) {
                v *= 0.125f;
                int hh = nn >> 6, hd = nn & 63;
                size_t o = ((size_t)(bb * HH + hh) * TQ + row) * HDD + hd;
                unsigned short hi = f2bf(v);
                q_hi[o] = hi; q_lo[o] = f2bf(v - bf2f(hi));
            } else if (nn < DD) {
                int hh = nn >> 6, hd = nn & 63;
                size_t o = ((size_t)(bb * HH + hh) * KLL + row) * HDD + hd;
                unsigned short hi = f2bf(v);
                k_hi[o] = hi; k_lo[o] = f2bf(v - bf2f(hi));
            } else {
                int n2 = nn - DD;
                int hh = n2 >> 6, hd = n2 & 63;
                size_t o = ((size_t)(bb * HH + hh) * KLL + row) * HDD + hd;
                unsigned short hi = f2bf(v);
                vr_hi[o] = hi; vr_lo[o] = f2bf(v - bf2f(hi));
            }
        }
    }
}

// Output projection: A = ao, W = wo (base passed), out f32 + tanh tail rows.
// 64-row LDS-staged structure (v16).
__global__ __launch_bounds__(256, 4)
void proj_out(const unsigned short* __restrict__ a_hi,
              const unsigned short* __restrict__ a_lo,
              const unsigned short* __restrict__ w_hi,
              const unsigned short* __restrict__ w_lo,
              const float* __restrict__ bias,
              float* __restrict__ out_f)
{
    const int tid = threadIdx.x;
    const int wv = tid >> 6;
    const int quad = (tid >> 4) & 3;
    const int colk = tid & 15;
    const int m0 = blockIdx.x * 64;
    const int n0 = blockIdx.y * 64;

    __shared__ unsigned short wls_h[2][64][40];
    __shared__ unsigned short wls_l[2][64][40];

    const int sn = tid >> 2;
    const int sk = (tid & 3) * 8;
    const unsigned short* wsrc_h = w_hi + (size_t)(n0 + sn) * DD + sk;
    const unsigned short* wsrc_l = w_lo + (size_t)(n0 + sn) * DD + sk;

    const int am = min(m0 + wv * 16 + colk, NROWS - 1);
    const unsigned short* arh = a_hi + (size_t)am * DD;
    const unsigned short* arl = a_lo + (size_t)am * DD;

    f32x4 acc[4] = {{0,0,0,0},{0,0,0,0},{0,0,0,0},{0,0,0,0}};

    {
        short8 sh = *(const short8*)(wsrc_h);
        short8 sl = *(const short8*)(wsrc_l);
        *(short8*)&wls_h[0][sn][sk] = sh;
        *(short8*)&wls_l[0][sn][sk] = sl;
    }
    __syncthreads();

    #pragma unroll 2
    for (int ks = 0; ks < 16; ++ks) {
        const int buf = ks & 1;
        const int k0 = ks * 32;
        short8 nh, nl;
        if (ks + 1 < 16) {
            nh = *(const short8*)(wsrc_h + k0 + 32);
            nl = *(const short8*)(wsrc_l + k0 + 32);
        }
        short8 ah = *(const short8*)(arh + k0 + quad * 8);
        short8 al = *(const short8*)(arl + k0 + quad * 8);
        #pragma unroll
        for (int nt = 0; nt < 4; ++nt) {
            short8 bh = *(const short8*)&wls_h[buf][nt * 16 + colk][quad * 8];
            short8 bl = *(const short8*)&wls_l[buf][nt * 16 + colk][quad * 8];
            acc[nt] = __builtin_amdgcn_mfma_f32_16x16x32_bf16(ah, bh, acc[nt], 0, 0, 0);
            acc[nt] = __builtin_amdgcn_mfma_f32_16x16x32_bf16(ah, bl, acc[nt], 0, 0, 0);
            acc[nt] = __builtin_amdgcn_mfma_f32_16x16x32_bf16(al, bh, acc[nt], 0, 0, 0);
        }
        if (ks + 1 < 16) {
            *(short8*)&wls_h[buf ^ 1][sn][sk] = nh;
            *(short8*)&wls_l[buf ^ 1][sn][sk] = nl;
        }
        __syncthreads();
    }

    #pragma unroll
    for (int nt = 0; nt < 4; ++nt) {
        const int nn = n0 + nt * 16 + colk;
        const float bv = bias[nn];
        #pragma unroll
        for (int reg = 0; reg < 4; ++reg) {
            const int m = m0 + wv * 16 + quad * 4 + reg;
            if (m >= NROWS) continue;
            float v = acc[nt][reg] + bv;
            int row = m >> 3;
            if (row >= TQ - MMEM) v = tanhf(v);
            out_f[(size_t)m * DD + nn] = v;
        }
    }
}

// Attention: v14 numerics EXACT + s_setprio(1) around MFMA clusters (T5).
__global__ __launch_bounds__(256, 3)
void attn_kernel(const unsigned short* __restrict__ qh_g,
                 const unsigned short* __restrict__ ql_g,
                 const unsigned short* __restrict__ kh_g,
                 const unsigned short* __restrict__ kl_g,
                 const unsigned short* __restrict__ vt_hi,
                 const unsigned short* __restrict__ vt_lo,
                 const int* __restrict__ lengths,
                 const unsigned int* __restrict__ pk2,
                 const unsigned short* __restrict__ rk_hi,
                 const unsigned short* __restrict__ rk_lo,
                 const float* __restrict__ rpe_v,
                 unsigned short* __restrict__ ao_hi,
                 unsigned short* __restrict__ ao_lo)
{
    // XCD-aware decode: xcd = id&7 fixed per head; t-chunks consecutive.
    const int id = blockIdx.x;
    const int xcd = id & 7;
    const int grp = id >> 3;             // 0..399
    const int t_chunk = grp % NTCH;
    const int n = (grp / NTCH) * 8 + xcd; // head index 0..63
    const int t0 = t_chunk * TB;
    const int rows = min(TB, TQ - t0);
    const int b = n >> 3;
    const int h = n & 7;
    const int tid = threadIdx.x;
    const int wv = tid >> 6;
    const int quad = (tid >> 4) & 3;
    const int colk = tid & 15;
    const int myk = wv * 16 + colk;

    __shared__ float qrk_l[TB][132];                 // qrk, then pr buckets (8448 B)
    __shared__ unsigned short p_hi[2][TB][72];       // 4608 B
    __shared__ unsigned short p_lo[2][TB][72];       // 4608 B
    __shared__ float4 stats_l[4][TB];                // 1024 B

    const int klen = lengths[b] + MMEM + RRCB;
    const int nch_live = (klen + CH - 1) / CH;       // block-uniform, 7..13
    const unsigned* pkg = pk2 + (size_t)t_chunk * 832 * 4;  // u32 units

#define LIVE(c) ((c) < MINCH || (c) < nch_live)

    // A fragments (Q), direct global, held all kernel. A row = query row colk.
    const int qrow = t0 + min(colk, rows - 1);
    const size_t qo = ((size_t)n * TQ + qrow) * HDD;
    short8 ah0 = *(const short8*)(qh_g + qo + quad * 8);
    short8 ah1 = *(const short8*)(qh_g + qo + 32 + quad * 8);
    short8 al0 = *(const short8*)(ql_g + qo + quad * 8);
    short8 al1 = *(const short8*)(ql_g + qo + 32 + quad * 8);

    // qrk via MFMA: wave wv does rpe_k row-tiles wv, wv+4, wv+8
    for (int t = wv; t < 9; t += 4) {
        const size_t rb = (size_t)(t * 16 + colk) * 64;
        short8 bh0 = *(const short8*)(rk_hi + rb + quad * 8);
        short8 bh1 = *(const short8*)(rk_hi + rb + 32 + quad * 8);
        short8 bl0 = *(const short8*)(rk_lo + rb + quad * 8);
        short8 bl1 = *(const short8*)(rk_lo + rb + 32 + quad * 8);
        f32x4 c4 = {0.f, 0.f, 0.f, 0.f};
        __builtin_amdgcn_s_setprio(1);
        c4 = __builtin_amdgcn_mfma_f32_16x16x32_bf16(ah0, bh0, c4, 0, 0, 0);
        c4 = __builtin_amdgcn_mfma_f32_16x16x32_bf16(ah1, bh1, c4, 0, 0, 0);
        c4 = __builtin_amdgcn_mfma_f32_16x16x32_bf16(ah0, bl0, c4, 0, 0, 0);
        c4 = __builtin_amdgcn_mfma_f32_16x16x32_bf16(ah1, bl1, c4, 0, 0, 0);
        c4 = __builtin_amdgcn_mfma_f32_16x16x32_bf16(al0, bh0, c4, 0, 0, 0);
        c4 = __builtin_amdgcn_mfma_f32_16x16x32_bf16(al1, bh1, c4, 0, 0, 0);
        __builtin_amdgcn_s_setprio(0);
        int c = t * 16 + colk;
        if (c <= 128) {
            #pragma unroll
            for (int reg = 0; reg < 4; ++reg) qrk_l[quad * 4 + reg][c] = c4[reg];
        }
    }
    __syncthreads();

    // ---- pass A: QK^T MFMA, record scores + max (live chunks only) ----
    float s_reg[NCH][4];
    float mx[4] = {-1e30f, -1e30f, -1e30f, -1e30f};

    #pragma unroll
    for (int cc = 0; cc < NCH; ++cc) {
        if (LIVE(cc)) {
            const int key = cc * CH + myk;
            const int krow = min(key, KLL - 1);
            const size_t ko = ((size_t)n * KLL + krow) * HDD;
            const unsigned r4 = pkg[key * 4 + quad];   // early: hides under MFMAs
            short8 bh0 = *(const short8*)(kh_g + ko + quad * 8);
            short8 bh1 = *(const short8*)(kh_g + ko + 32 + quad * 8);
            short8 bl0 = *(const short8*)(kl_g + ko + quad * 8);
            short8 bl1 = *(const short8*)(kl_g + ko + 32 + quad * 8);
            f32x4 c4a = {0.f, 0.f, 0.f, 0.f};
            f32x4 c4b = {0.f, 0.f, 0.f, 0.f};
            __builtin_amdgcn_s_setprio(1);
            c4a = __builtin_amdgcn_mfma_f32_16x16x32_bf16(ah0, bh0, c4a, 0, 0, 0);
            c4b = __builtin_amdgcn_mfma_f32_16x16x32_bf16(ah1, bh1, c4b, 0, 0, 0);
            c4a = __builtin_amdgcn_mfma_f32_16x16x32_bf16(ah0, bl0, c4a, 0, 0, 0);
            c4b = __builtin_amdgcn_mfma_f32_16x16x32_bf16(ah1, bl1, c4b, 0, 0, 0);
            c4a = __builtin_amdgcn_mfma_f32_16x16x32_bf16(al0, bh0, c4a, 0, 0, 0);
            c4b = __builtin_amdgcn_mfma_f32_16x16x32_bf16(al1, bh1, c4b, 0, 0, 0);
            __builtin_amdgcn_s_setprio(0);

            const bool vkey = (key < klen);
            #pragma unroll
            for (int reg = 0; reg < 4; ++reg) {
                const int row = quad * 4 + reg;
                const unsigned rid = (r4 >> (8 * reg)) & 255u;
                const float qv = qrk_l[row][min(rid, 128u)];   // clamped gather
                float s = (c4a[reg] + c4b[reg]) + qv;
                const bool ok = vkey && (row < rows) && (rid != 255u);
                s = ok ? s : -1e30f;
                mx[reg] = fmaxf(mx[reg], s);
                s_reg[cc][reg] = s;
            }
        } else {
            #pragma unroll
            for (int reg = 0; reg < 4; ++reg) s_reg[cc][reg] = -1e30f;
        }
    }

    // max merge: shfl16 then cross-wave
    #pragma unroll
    for (int reg = 0; reg < 4; ++reg)
        #pragma unroll
        for (int d = 1; d < 16; d <<= 1) mx[reg] = fmaxf(mx[reg], __shfl_xor(mx[reg], d, 16));
    if (colk == 0) {
        #pragma unroll
        for (int reg = 0; reg < 4; ++reg)
            stats_l[wv][quad * 4 + reg] = make_float4(mx[reg], 0.f, 0.f, 0.f);
    }
    __syncthreads();
    if (tid < TB) {
        float M = fmaxf(fmaxf(stats_l[0][tid].x, stats_l[1][tid].x),
                        fmaxf(stats_l[2][tid].x, stats_l[3][tid].x));
        stats_l[0][tid].x = M;
    }
    __syncthreads();

    // e-sweep (branchless): e = exp(s - M) (underflows to 0 for dead),
    // overwrite s_reg; accumulate l, l2, count (count via select).
    float Mr[4], l[4] = {0,0,0,0}, l2[4] = {0,0,0,0}, cn[4] = {0,0,0,0};
    #pragma unroll
    for (int reg = 0; reg < 4; ++reg) Mr[reg] = stats_l[0][quad * 4 + reg].x;
    #pragma unroll
    for (int cc = 0; cc < NCH; ++cc) {
        if (LIVE(cc)) {
            #pragma unroll
            for (int reg = 0; reg < 4; ++reg) {
                float s = s_reg[cc][reg];
                float e = expf(s - Mr[reg]);
                cn[reg] += (s > -1e29f) ? 1.f : 0.f;
                l[reg] += e;
                l2[reg] = fmaf(e, e, l2[reg]);
                s_reg[cc][reg] = e;
            }
        }
    }
    #pragma unroll
    for (int reg = 0; reg < 4; ++reg)
        #pragma unroll
        for (int d = 1; d < 16; d <<= 1) {
            l[reg]  += __shfl_xor(l[reg], d, 16);
            l2[reg] += __shfl_xor(l2[reg], d, 16);
            cn[reg] += __shfl_xor(cn[reg], d, 16);
        }
    if (colk == 0) {
        #pragma unroll
        for (int reg = 0; reg < 4; ++reg)
            stats_l[wv][quad * 4 + reg] = make_float4(Mr[reg], l[reg], l2[reg], cn[reg]);
    }
    __syncthreads();
    if (tid < TB) {
        float L = 0.f, L2 = 0.f, C = 0.f;
        #pragma unroll
        for (int w = 0; w < 4; ++w) {
            float4 s4 = stats_l[w][tid];
            L += s4.y; L2 += s4.z; C += s4.w;
        }
        float inv = (L > 0.f) ? 1.f / L : 0.f;
        float mean = 1.f / (C + 1e-8f);
        float sump2 = L2 * inv * inv;
        float var = (sump2 - 2.f * mean + C * mean * mean) / (C - 1.f + 1e-8f);
        var = fmaxf(var, 0.f);
        float thr = mean - 0.5f * sqrtf(var);
        stats_l[0][tid] = make_float4(stats_l[0][tid].x, inv, thr, 0.f);
    }
    // zero pr (qrk_l reuse; scores are stored, qrk dead after pass A)
    for (int i = tid; i < TB * 132; i += 256) ((float*)qrk_l)[i] = 0.f;
    __syncthreads();

    // ---- pass B: p = e*inv, threshold, buckets, PV via MFMA (live only) ----
    float inv_r[4], thr_r[4];
    #pragma unroll
    for (int reg = 0; reg < 4; ++reg) {
        float4 s4 = stats_l[0][quad * 4 + reg];
        inv_r[reg] = s4.y; thr_r[reg] = s4.z;
    }
    float sig[4] = {0.f, 0.f, 0.f, 0.f};
    f32x4 oaccA = {0.f, 0.f, 0.f, 0.f};
    f32x4 oaccB = {0.f, 0.f, 0.f, 0.f};

    auto computeP = [&](int cc, int buf, unsigned r4) {
        #pragma unroll
        for (int reg = 0; reg < 4; ++reg) {
            const int row = quad * 4 + reg;
            float p = s_reg[cc][reg] * inv_r[reg];
            if (p < thr_r[reg]) p = 0.f;
            sig[reg] += p;
            if (p > 0.f) {
                unsigned rid = (r4 >> (8 * reg)) & 255u;
                atomicAdd(&qrk_l[row][rid], p);
            }
            unsigned short ph = f2bf(p);
            p_hi[buf][row][myk] = ph;
            p_lo[buf][row][myk] = f2bf(p - bf2f(ph));
        }
    };

    // V fragment registers (current + prefetch handled per iteration)
    short8 vh0, vh1, vl0, vl1;
    {
        const size_t vbase = ((size_t)n * HDD + wv * 16 + colk) * VTS;
        vh0 = *(const short8*)(vt_hi + vbase + quad * 8);
        vh1 = *(const short8*)(vt_hi + vbase + 32 + quad * 8);
        vl0 = *(const short8*)(vt_lo + vbase + quad * 8);
        vl1 = *(const short8*)(vt_lo + vbase + 32 + quad * 8);
    }
    computeP(0, 0, pkg[myk * 4 + quad]);
    __syncthreads();
    #pragma unroll
    for (int cc = 0; cc < NCH; ++cc) {
        if (LIVE(cc)) {
            const bool nlive = (cc + 1 < NCH) && LIVE(cc + 1);
            // prefetch next chunk's V frags + pk word (global: no barrier dep)
            short8 nvh0, nvh1, nvl0, nvl1; unsigned nr4 = 0;
            if (nlive) {
                const size_t vbase = ((size_t)n * HDD + wv * 16 + colk) * VTS
                                   + (cc + 1) * CH;
                nvh0 = *(const short8*)(vt_hi + vbase + quad * 8);
                nvh1 = *(const short8*)(vt_hi + vbase + 32 + quad * 8);
                nvl0 = *(const short8*)(vt_lo + vbase + quad * 8);
                nvl1 = *(const short8*)(vt_lo + vbase + 32 + quad * 8);
                nr4 = pkg[((cc + 1) * CH + myk) * 4 + quad];
            }
            const int buf = cc & 1;
            short8 ph0 = *(const short8*)&p_hi[buf][colk][quad * 8];
            short8 ph1 = *(const short8*)&p_hi[buf][colk][32 + quad * 8];
            short8 pl0 = *(const short8*)&p_lo[buf][colk][quad * 8];
            short8 pl1 = *(const short8*)&p_lo[buf][colk][32 + quad * 8];
            __builtin_amdgcn_s_setprio(1);
            oaccA = __builtin_amdgcn_mfma_f32_16x16x32_bf16(vh0, ph0, oaccA, 0, 0, 0);
            oaccB = __builtin_amdgcn_mfma_f32_16x16x32_bf16(vh1, ph1, oaccB, 0, 0, 0);
            oaccA = __builtin_amdgcn_mfma_f32_16x16x32_bf16(vh0, pl0, oaccA, 0, 0, 0);
            oaccB = __builtin_amdgcn_mfma_f32_16x16x32_bf16(vh1, pl1, oaccB, 0, 0, 0);
            oaccA = __builtin_amdgcn_mfma_f32_16x16x32_bf16(vl0, ph0, oaccA, 0, 0, 0);
            oaccB = __builtin_amdgcn_mfma_f32_16x16x32_bf16(vl1, ph1, oaccB, 0, 0, 0);
            __builtin_amdgcn_s_setprio(0);
            if (nlive) computeP(cc + 1, (cc + 1) & 1, nr4);
            __syncthreads();
            if (nlive) { vh0 = nvh0; vh1 = nvh1; vl0 = nvl0; vl1 = nvl1; }
        }
    }

    // survivor-sum merge
    #pragma unroll
    for (int reg = 0; reg < 4; ++reg)
        #pragma unroll
        for (int d = 1; d < 16; d <<= 1) sig[reg] += __shfl_xor(sig[reg], d, 16);
    if (colk == 0) {
        #pragma unroll
        for (int reg = 0; reg < 4; ++reg)
            stats_l[wv][quad * 4 + reg].w = sig[reg];
    }
    __syncthreads();
    if (tid < TB) {
        float S = stats_l[0][tid].w + stats_l[1][tid].w + stats_l[2][tid].w + stats_l[3][tid].w;
        stats_l[0][tid].w = (S > 0.f) ? 1.f / S : 0.f;
    }
    __syncthreads();

    // output: lane owns O[row=colk][hd = wv*16 + quad*4 .. +3], bf16 hi/lo.
    // Branchless bucket dot: p == 0 contributes exactly 0, loads pipeline.
    if (colk < rows) {
        float4 ar = {0.f, 0.f, 0.f, 0.f};
        const int hdb = wv * 16 + quad * 4;
        #pragma unroll 4
        for (int c = 0; c < 129; ++c) {
            float p = qrk_l[colk][c];
            float4 v4 = *(const float4*)(rpe_v + (size_t)c * HDD + hdb);
            ar.x = fmaf(p, v4.x, ar.x);
            ar.y = fmaf(p, v4.y, ar.y);
            ar.z = fmaf(p, v4.z, ar.z);
            ar.w = fmaf(p, v4.w, ar.w);
        }
        const float invS = stats_l[0][colk].w;
        float o0 = (2.f * (oaccA[0] + oaccB[0]) + ar.x) * invS;
        float o1 = (2.f * (oaccA[1] + oaccB[1]) + ar.y) * invS;
        float o2 = (2.f * (oaccA[2] + oaccB[2]) + ar.z) * invS;
        float o3 = (2.f * (oaccA[3] + oaccB[3]) + ar.w) * invS;
        size_t oo = ((size_t)(t0 + colk) * BB + b) * DD + h * HDD + hdb;
        ushort4 oh, ol;
        oh.x = f2bf(o0); ol.x = f2bf(o0 - bf2f(oh.x));
        oh.y = f2bf(o1); ol.y = f2bf(o1 - bf2f(oh.y));
        oh.z = f2bf(o2); ol.z = f2bf(o2 - bf2f(oh.z));
        oh.w = f2bf(o3); ol.w = f2bf(o3 - bf2f(oh.w));
        *(ushort4*)(ao_hi + oo) = oh;
        *(ushort4*)(ao_lo + oo) = ol;
    }
#undef LIVE
}

extern "C" void kernel_launch(void* const* d_in, const int* in_sizes, int n_in,
                              void* d_out, int out_size, void* d_ws, size_t ws_size,
                              hipStream_t stream) {
    const float*          x      = (const float*)d_in[0];
    const int*            lengths= (const int*)d_in[1];
    const float*          mems   = (const float*)d_in[2];
    const void*           amask  = (const void*)d_in[3];
    const int*            rpe    = (const int*)d_in[4];
    const float*          wq     = (const float*)d_in[6];
    const float*          bq     = (const float*)d_in[7];
    const float*          wkv    = (const float*)d_in[8];
    const float*          bkv    = (const float*)d_in[9];
    const float*          wo     = (const float*)d_in[10];
    const float*          bo     = (const float*)d_in[11];
    const float*          rpe_k  = (const float*)d_in[12];
    const float*          rpe_v  = (const float*)d_in[13];

    const size_t NE = (size_t)NROWS * DD;           // 3,268,608
    const size_t VTN = (size_t)NHEADS * HDD * VTS;  // 3,407,872

    char* p = (char*)d_ws;
    unsigned short* q_hi = (unsigned short*)p;  p += NE * 2;
    unsigned short* q_lo = (unsigned short*)p;  p += NE * 2;
    // union region: xs/ms (proj inputs, dead after proj) | vt (written after)
    char* uni = p;                              p += VTN * 4;   // vt is the larger
    unsigned short* xs_hi = (unsigned short*)uni;
    unsigned short* xs_lo = xs_hi + NE;
    unsigned short* ms_hi = xs_lo + NE;
    unsigned short* ms_lo = ms_hi + 48 * DD;
    unsigned short* vt_hi = (unsigned short*)uni;
    unsigned short* vt_lo = vt_hi + VTN;
    unsigned short* w_hi = (unsigned short*)p;  p += (size_t)2048 * DD * 2;
    unsigned short* w_lo = (unsigned short*)p;  p += (size_t)2048 * DD * 2;
    unsigned short* k_hi = (unsigned short*)p;  p += NE * 2;
    unsigned short* k_lo = (unsigned short*)p;  p += NE * 2;
    unsigned short* vr_hi = (unsigned short*)p; p += NE * 2;   // aliased by ao after transpose
    unsigned short* vr_lo = (unsigned short*)p; p += NE * 2;
    unsigned short* ao_hi = vr_hi;
    unsigned short* ao_lo = vr_lo;
    unsigned short* rk_hi = (unsigned short*)p; p += 144 * 64 * 2;
    unsigned short* rk_lo = (unsigned short*)p; p += 144 * 64 * 2;
    unsigned int*   pk2   = (unsigned int*)p;   p += (size_t)NTCH * 832 * 16;

    {
        const size_t sp_total = NE + (size_t)48 * DD + (size_t)2048 * DD;  // 4,341,760
        const int sp_blocks = (int)((sp_total + 1023) / 1024);             // 4,240
        prep_kernel<<<PK2_BLOCKS + RK_BLOCKS + sp_blocks, 256, 0, stream>>>(
            amask, rpe, pk2,
            rpe_k, rk_hi, rk_lo,
            x, mems, wq, wkv, wo,
            xs_hi, xs_lo, ms_hi, ms_lo, w_hi, w_lo);
    }
    proj_qkv64<<<dim3(100, 24), 256, 0, stream>>>(
        xs_hi, xs_lo, ms_hi, ms_lo, w_hi, w_lo, bq, bkv,
        q_hi, q_lo, k_hi, k_lo, vr_hi, vr_lo);
    transpose_v_kernel<<<dim3(13, NHEADS), 256, 0, stream>>>(vr_hi, vr_lo, vt_hi, vt_lo);
    attn_kernel<<<3200, 256, 0, stream>>>(
        q_hi, q_lo, k_hi, k_lo, vt_hi, vt_lo, lengths, pk2, rk_hi, rk_lo, rpe_v, ao_hi, ao_lo);
    proj_out<<<dim3(100, 8), 256, 0, stream>>>(
        ao_hi, ao_lo, w_hi + (size_t)1536 * DD, w_lo + (size_t)1536 * DD, bo,
        (float*)d_out);
}